// Round 11
// baseline (191.734 us; speedup 1.0000x reference)
//
#include <hip/hip_runtime.h>
#include <hip/hip_bf16.h>
#include <type_traits>

typedef __hip_bfloat16 bf16;
typedef short bf16x8 __attribute__((ext_vector_type(8)));
typedef float f32x4 __attribute__((ext_vector_type(4)));
typedef short short4_ __attribute__((ext_vector_type(4)));

#define NB 8      // batch
#define SM 512    // block size M
#define SL 1024   // attn span L
#define SH 512    // hidden
#define NH 8      // heads
#define HD 64     // head dim
#define SN 1536   // M + L (key length)

static __device__ __forceinline__ short bf_bits(float x) {
  union { bf16 b; short s; } u; u.b = __float2bfloat16(x); return u.s;
}
static __device__ __forceinline__ bf16x8 ld8any(const bf16* p) {
  return *reinterpret_cast<const bf16x8*>(p);
}
static __device__ __forceinline__ bf16x8 ld8any(const float* p) {
  float4 a = *reinterpret_cast<const float4*>(p);
  float4 b = *reinterpret_cast<const float4*>(p + 4);
  bf16x8 r;
  r[0] = bf_bits(a.x); r[1] = bf_bits(a.y); r[2] = bf_bits(a.z); r[3] = bf_bits(a.w);
  r[4] = bf_bits(b.x); r[5] = bf_bits(b.y); r[6] = bf_bits(b.z); r[7] = bf_bits(b.w);
  return r;
}
static __device__ __forceinline__ void st1(bf16* p, float v) { *p = __float2bfloat16(v); }
static __device__ __forceinline__ void st1(float* p, float v) { *p = v; }
static __device__ __forceinline__ f32x4 mfma16(bf16x8 a, bf16x8 b, f32x4 c) {
  return __builtin_amdgcn_mfma_f32_16x16x32_bf16(a, b, c, 0, 0, 0);
}

// ---------------------------------------------------------------------------
// Universal fragment-linear layout for an [R x C] matrix (C = 512):
//   FRAGIDX(row,col) = (row>>4)*8192 + (col>>5)*512
//                    + ((col>>3)&3)*128 + (row&15)*8 + (col&7)
// One wave MFMA fragment (16 rows x 32 cols) = 1KB contiguous, lane*16B.
// ---------------------------------------------------------------------------

// ---------------------------------------------------------------------------
// prep_small: ONLY weights + pe (key/value/query conversion is now fused
// into the projection GEMMs).  id<128: W LDS-transpose conv (4 x 32 tiles).
// id in [128,384): pe -> peF  (256 blocks x 256 thr = 65536 el — FULL
// coverage; rounds 9-10 only wrote 8192 el, a latent bug masked by ws=0).
// ---------------------------------------------------------------------------
__global__ __launch_bounds__(256) void prep_small(
    const float* __restrict__ Wq, const float* __restrict__ Wk,
    const float* __restrict__ Wv, const float* __restrict__ Wo,
    const float* __restrict__ pe,
    bf16* __restrict__ Wb, bf16* __restrict__ peF) {
  __shared__ __align__(16) bf16 t[16 * 520];
  const int id = blockIdx.x, tid = threadIdx.x;
  if (id < 128) {
    const float* ws_[4] = {Wq, Wk, Wv, Wo};
    const float* src = ws_[id >> 5] + (size_t)(id & 31) * 8192;
    bf16* dst = Wb + (size_t)(id >> 5) * 262144 + (size_t)(id & 31) * 8192;
#pragma unroll
    for (int j = 0; j < 4; ++j) {
      const int i = j * 2048 + tid * 8;
      const bf16x8 v = ld8any(src + i);
      *reinterpret_cast<bf16x8*>(&t[(i >> 9) * 520 + (i & 511)]) = v;
    }
    __syncthreads();
#pragma unroll
    for (int j = 0; j < 4; ++j) {
      const int a = j * 2048 + tid * 8;
      const int kt5 = a >> 9, rest = a & 511;
      const int q = rest >> 7, rowl = (rest >> 3) & 15;
      *reinterpret_cast<bf16x8*>(dst + a) =
          *reinterpret_cast<const bf16x8*>(&t[rowl * 520 + kt5 * 32 + q * 8]);
    }
  } else {
    const int idx = (id - 128) * 256 + tid;   // 0..65535, full peF
    const int l = idx >> 6, d = idx & 63;
    peF[(size_t)((l >> 4) * 2 + (d >> 5)) * 512
        + (size_t)((((d >> 3) & 3) * 16 + (l & 15)) * 8 + (d & 7))]
      = __float2bfloat16(pe[d * SL + l]);
  }
}

// ---------------------------------------------------------------------------
// gemm_f32dev: Y = X @ W^T with X ROW-MAJOR F32 (converted on the fly via
// fragment-linear LDS staging, double-buffered; f32 loads issued before the
// MFMA phase, ds_write after it -> HBM latency hidden under MFMA).  W is
// fragment-linear bf16.  BM=128 x BN=128, 4 waves, wave tile 64x64.
// MODE 1: kF out.  MODE 2: vF out (LDS transpose, reuses lds after K-loop).
// MODE 3: qpF out.
// ---------------------------------------------------------------------------
#define T2STR 136

#define WLOADF(BF, KT)                                                       \
  {                                                                          \
    BF[0] = ld8any(wr +         (size_t)(KT) * 512);                         \
    BF[1] = ld8any(wr + 8192  + (size_t)(KT) * 512);                         \
    BF[2] = ld8any(wr + 16384 + (size_t)(KT) * 512);                         \
    BF[3] = ld8any(wr + 24576 + (size_t)(KT) * 512);                         \
  }

template <int MODE>
static __device__ __forceinline__ void gemm_f32dev(
    const float* __restrict__ X, const bf16* __restrict__ WF,
    bf16* __restrict__ Y, int xblk, int yblk, bf16* lds) {
  const int tid  = threadIdx.x;
  const int lane = tid & 63, w = tid >> 6;
  const int col16 = lane & 15, quad = lane >> 4;
  const int lane8 = lane * 8;
  const int wm = w >> 1, wn = w & 1;
  const int m0 = xblk * 128 + wm * 64;
  const int n0 = yblk * 128 + wn * 64;
  const bf16* wr = WF + (size_t)(n0 >> 4) * 8192 + lane8;

  // staging mapping: j=0..3, row = j*32 + (tid>>3), col = (tid&7)*4
  const int srow_ = tid >> 3, sc_ = (tid & 7) * 4;
  const float* xb = X + (size_t)(xblk * 128) * 512;

  auto xload = [&](int KT, float4* x4) {
#pragma unroll
    for (int j = 0; j < 4; ++j)
      x4[j] = *reinterpret_cast<const float4*>(
          xb + (size_t)(j * 32 + srow_) * 512 + KT * 32 + sc_);
  };
  auto xwrite = [&](int BUF, const float4* x4) {
#pragma unroll
    for (int j = 0; j < 4; ++j) {
      const int row = j * 32 + srow_;
      const int el = BUF * 4096 + (row >> 4) * 512
                   + ((sc_ >> 3) & 3) * 128 + (row & 15) * 8 + (sc_ & 7);
      short4_ pk;
      pk[0] = bf_bits(x4[j].x); pk[1] = bf_bits(x4[j].y);
      pk[2] = bf_bits(x4[j].z); pk[3] = bf_bits(x4[j].w);
      *reinterpret_cast<short4_*>(lds + el) = pk;
    }
  };

  f32x4 acc[4][4];
#pragma unroll
  for (int i = 0; i < 4; ++i)
#pragma unroll
    for (int j = 0; j < 4; ++j) acc[i][j] = f32x4{0.f,0.f,0.f,0.f};

  bf16x8 wA[4], wB[4];
  {
    float4 xc[4];
    xload(0, xc);
    WLOADF(wA, 0);
    __builtin_amdgcn_sched_barrier(0);
    xwrite(0, xc);
  }
  __syncthreads();

#pragma unroll
  for (int kt = 0; kt < 16; ++kt) {
    float4 xn[4];
    if (kt < 15) {
      xload(kt + 1, xn);
      if (kt & 1) { WLOADF(wA, kt + 1); } else { WLOADF(wB, kt + 1); }
      __builtin_amdgcn_sched_barrier(0);
    }
    bf16x8 af[4];
#pragma unroll
    for (int t = 0; t < 4; ++t)
      af[t] = ld8any(lds + (kt & 1) * 4096 + (wm * 4 + t) * 512 + lane8);
#pragma unroll
    for (int mt = 0; mt < 4; ++mt)
#pragma unroll
      for (int nt = 0; nt < 4; ++nt)
        acc[mt][nt] = mfma16(af[mt], (kt & 1) ? wB[nt] : wA[nt], acc[mt][nt]);
    if (kt < 15) xwrite((kt + 1) & 1, xn);
    __syncthreads();
  }

  if constexpr (MODE == 1) {
    // kF: head h = n0>>6; within-half idx = key8 + q*128 + de.
    const int dq = col16 >> 3, de = col16 & 7;
    const int head = n0 >> 6;
#pragma unroll
    for (int mt = 0; mt < 4; ++mt)
#pragma unroll
      for (int r = 0; r < 4; ++r) {
        const int row = m0 + mt*16 + quad*4 + r;
        const int b = row / SN, sr = row - b * SN;
        bf16* yr = (bf16*)Y
            + (((size_t)(b*NH + head)*96 + (sr>>4))*2)*512
            + (size_t)((sr&15)*8 + de);
#pragma unroll
        for (int nt = 0; nt < 4; ++nt)
          yr[(nt>>1)*512 + ((nt&1)*2 + dq)*128] = __float2bfloat16(acc[mt][nt][r]);
      }
  } else if constexpr (MODE == 3) {
    const int dq = col16 >> 3, de = col16 & 7;
    const int c5b = n0 >> 5;
#pragma unroll
    for (int mt = 0; mt < 4; ++mt)
#pragma unroll
      for (int r = 0; r < 4; ++r) {
        bf16* yr = (bf16*)Y + (size_t)((m0>>4) + mt) * 8192
                 + (size_t)((quad*4 + r)*8 + de);
#pragma unroll
        for (int nt = 0; nt < 4; ++nt)
          yr[(c5b + (nt>>1))*512 + ((nt&1)*2 + dq)*128] = __float2bfloat16(acc[mt][nt][r]);
      }
  } else {
    // vF via LDS transpose: lds[d 0..127][row_loc 0..127] (post-loop reuse)
    bf16* tile = lds;
#pragma unroll
    for (int mt = 0; mt < 4; ++mt)
#pragma unroll
      for (int r = 0; r < 4; ++r) {
        const int row_loc = wm*64 + mt*16 + quad*4 + r;
#pragma unroll
        for (int nt = 0; nt < 4; ++nt) {
          const int d = wn*64 + nt*16 + col16;
          tile[d * T2STR + row_loc] = __float2bfloat16(acc[mt][nt][r]);
        }
      }
    __syncthreads();
    const int d  = tid >> 1;      // 0..127
    const int hq = tid & 1;       // 64-row half
    const bf16* src = tile + d * T2STR + hq * 64;
    const int row0 = xblk*128 + hq*64;
    const int b = row0 / SN, sr0 = row0 - b * SN;
    const int head = yblk*2 + (d >> 6);
    const int dd = d & 63;
    bf16* dstF = (bf16*)Y + (((size_t)(b*NH + head)*4 + (dd>>4))*96)*256
               + (size_t)(dd&15)*8;
#pragma unroll
    for (int i = 0; i < 8; ++i) {
      const int key = sr0 + i*8;
      const size_t off = (size_t)(key>>4)*256 + (size_t)((key>>3)&1)*128;
      *reinterpret_cast<uint4*>(dstF + off) = reinterpret_cast<const uint4*>(src)[i];
    }
  }
}

// Merged K+Q+V projection (single launch; no staging buffers):
//  [0,384):   K-proj  key f32   -> kF  (B2)
//  [384,512): Q-proj  query f32 -> qpF (qp)
//  [512,896): V-proj  value f32 -> vF  (B0)
__global__ __launch_bounds__(256, 2) void gemmKQV(
    const float* __restrict__ key, const float* __restrict__ query,
    const float* __restrict__ value,
    const bf16* __restrict__ Wk_b, const bf16* __restrict__ Wq_b,
    const bf16* __restrict__ Wv_b,
    bf16* __restrict__ kF, bf16* __restrict__ qpF, bf16* __restrict__ vF) {
  __shared__ __align__(16) bf16 lds[128 * T2STR];  // 34.8KB (union w/ staging)
  const int id = blockIdx.x;
  if (id < 384)      gemm_f32dev<1>(key,   Wk_b, kF,  id >> 2,         id & 3, lds);
  else if (id < 512) gemm_f32dev<3>(query, Wq_b, qpF, (id - 384) >> 2, id & 3, lds);
  else               gemm_f32dev<2>(value, Wv_b, vF,  (id - 512) >> 2, id & 3, lds);
}

// ---------------------------------------------------------------------------
// gemmO: 64x32 wave tile (BM=128, BN=64), grid 256 -> full-GPU coverage.
// X (ctx) and W fragment-linear, register double-buffered.
// ---------------------------------------------------------------------------
#define GLO(AF, BF, KT)                                                      \
  {                                                                          \
    AF[0] = ld8any(xr +         (size_t)(KT) * 512);                         \
    AF[1] = ld8any(xr + 8192  + (size_t)(KT) * 512);                         \
    AF[2] = ld8any(xr + 16384 + (size_t)(KT) * 512);                         \
    AF[3] = ld8any(xr + 24576 + (size_t)(KT) * 512);                         \
    BF[0] = ld8any(wr +         (size_t)(KT) * 512);                         \
    BF[1] = ld8any(wr + 8192  + (size_t)(KT) * 512);                         \
  }

__global__ __launch_bounds__(256, 2) void gemmO(
    const bf16* __restrict__ XF, const bf16* __restrict__ WF, float* __restrict__ Y) {
  const int id   = blockIdx.x;
  const int s_   = id >> 3;
  const int xblk = (id & 7) + 8 * (s_ >> 3);
  const int yblk = s_ & 7;
  const int tid  = threadIdx.x;
  const int lane = tid & 63, w = tid >> 6;
  const int col16 = lane & 15, quad = lane >> 4;
  const int lane8 = lane * 8;
  const int wm = w >> 1, wn = w & 1;
  const int m0 = xblk * 128 + wm * 64;
  const int n0 = yblk * 64 + wn * 32;
  const bf16* xr = XF + (size_t)(m0 >> 4) * 8192 + lane8;
  const bf16* wr = WF + (size_t)(n0 >> 4) * 8192 + lane8;
  f32x4 acc[4][2];
#pragma unroll
  for (int i = 0; i < 4; ++i)
#pragma unroll
    for (int j = 0; j < 2; ++j) acc[i][j] = f32x4{0.f,0.f,0.f,0.f};

  bf16x8 afA[4], bfA[2], afB[4], bfB[2];
  GLO(afA, bfA, 0);
  __builtin_amdgcn_sched_barrier(0);
#pragma unroll
  for (int kt = 0; kt < 16; kt += 2) {
    GLO(afB, bfB, kt + 1);
    __builtin_amdgcn_sched_barrier(0);
#pragma unroll
    for (int mt = 0; mt < 4; ++mt)
#pragma unroll
      for (int nt = 0; nt < 2; ++nt)
        acc[mt][nt] = mfma16(afA[mt], bfA[nt], acc[mt][nt]);
    const int ktn = (kt + 2 < 16) ? kt + 2 : kt;
    GLO(afA, bfA, ktn);
    __builtin_amdgcn_sched_barrier(0);
#pragma unroll
    for (int mt = 0; mt < 4; ++mt)
#pragma unroll
      for (int nt = 0; nt < 2; ++nt)
        acc[mt][nt] = mfma16(afB[mt], bfB[nt], acc[mt][nt]);
  }
#pragma unroll
  for (int mt = 0; mt < 4; ++mt)
#pragma unroll
    for (int r = 0; r < 4; ++r) {
      const int row = m0 + mt*16 + quad*4 + r;
      float* yr = Y + (size_t)row * SH + n0 + col16;
      yr[0]  = acc[mt][0][r];
      yr[16] = acc[mt][1][r];
    }
}

// ---------------------------------------------------------------------------
// Barrier-free wave-private fused attention (round-10 proven, ~45 us).
// One 64-lane wave owns 16 query rows; grid 2048 x 64 threads.
// Operand-swapped MFMAs keep lane&15 == query-row in EVERY phase; coalesced
// 1KB fragment loads; sched_barrier-pinned register prefetch; mask-fold +
// affine mv ramp + defer-max (T13) softmax.
// ---------------------------------------------------------------------------
#define PSTR1 69    // pos stride (f32): scalar writes, b128-aligned reads
#define BSTR1 104   // P stride (bf16): b64 writes, b128 reads aligned

__global__ __launch_bounds__(64, 2) void attn1w(
    const bf16* __restrict__ qp, const bf16* __restrict__ Kh,
    const bf16* __restrict__ VT, const bf16* __restrict__ peT,
    const float* __restrict__ spanv, bf16* __restrict__ ctx) {
  __shared__ __align__(16) float pos_s[16 * PSTR1];
  __shared__ __align__(16) bf16  P_s[16 * BSTR1];

  const int id = blockIdx.x;
  const int h  = id & 7;
  const int s_ = id >> 3;
  const int m0 = (s_ & 31) * 16;
  const int b  = s_ >> 5;
  const int hb = b * 8 + h;
  const int lane  = threadIdx.x;
  const int col16 = lane & 15, quad = lane >> 4, kq = quad << 3;
  const int q4 = quad << 2;
  const int lane8 = lane * 8;

  // zero P band once (cols 80..103 stay zero; read by ks=2 PV fragment)
  for (int i = lane; i < 16 * BSTR1; i += 64)
    P_s[i] = __float2bfloat16(0.0f);

  // q from fragment-linear qp: rt*8192 + h*1024 + lane*8 (and +512)
  const bf16* qb = qp + (size_t)((b*SM + m0) >> 4) * 8192 + h*1024 + lane8;
  const bf16x8 qf0 = ld8any(qb), qf1 = ld8any(qb + 512);

  const bf16* kbF = Kh + (size_t)hb * 98304 + lane8;   // 96 tiles * 1024
  const bf16* vbF = VT + (size_t)hb * 98304 + lane8;   // 4 dt * 96 kt * 256
  const bf16* pbF = peT + lane8;

  float Mrun = -1.0e30f, Srun = 0.0f;
  const float span1024 = spanv[h] * 1024.0f;
  f32x4 o[4];
#pragma unroll
  for (int dt = 0; dt < 4; ++dt) o[dt] = f32x4{0.f,0.f,0.f,0.f};

  // loop-invariant per-lane softmax constants
  float bias_[5][4], mvs_[5][4];
  {
    const float mvb = ((float)(q4 - col16 - 1023) + span1024) * 0.03125f + 1.0f;
#pragma unroll
    for (int t = 0; t < 5; ++t)
#pragma unroll
      for (int r = 0; r < 4; ++r) {
        const int l = 16*t + q4 + r - col16;
        bias_[t][r] = ((unsigned)l < 64u) ? 0.0f : -1.0e30f;
        mvs_[t][r]  = mvb + (float)(16*t + r) * 0.03125f;
      }
  }

  // prefetched operand fragments (single-buffered; WAR ordering via reg deps)
  bf16x8 kf[5][2], pf[4][2], vf[4][3];

  // ---- prologue: chunk-0 operands ----
  {
    const int tk0 = m0 >> 4;
#pragma unroll
    for (int t = 0; t < 5; ++t) {
      const bf16* kr = kbF + (size_t)(tk0 + t) * 1024;
      kf[t][0] = ld8any(kr); kf[t][1] = ld8any(kr + 512);
    }
#pragma unroll
    for (int t = 0; t < 4; ++t) {
      const bf16* pr = pbF + (size_t)t * 1024;
      pf[t][0] = ld8any(pr); pf[t][1] = ld8any(pr + 512);
    }
#pragma unroll
    for (int dt = 0; dt < 4; ++dt) {
      const bf16* v0 = vbF + (size_t)dt * 24576 + (size_t)tk0 * 256;
#pragma unroll
      for (int ks = 0; ks < 3; ++ks) vf[dt][ks] = ld8any(v0 + ks*512);
    }
    __builtin_amdgcn_sched_barrier(0);
  }

  const int posw = col16 * PSTR1 + q4;        // write base (scalar f32)
  const int posr = col16 * (PSTR1 - 1) + q4;  // read base (b128-aligned)
  const int pww  = col16 * BSTR1 + q4;        // P write base (b64-aligned)
  const int pwr  = col16 * BSTR1 + kq;        // P read base (b128-aligned)

  for (int ch = 0; ch < 16; ++ch) {
    const int l0 = ch << 6;

    // ---- pos MFMAs (swapped: A=pe rows, D rows = l, cols = q-row) ----
    f32x4 pacc[4];
#pragma unroll
    for (int t = 0; t < 4; ++t) {
      f32x4 a = {0.f,0.f,0.f,0.f};
      a = mfma16(pf[t][0], qf0, a);
      a = mfma16(pf[t][1], qf1, a);
      pacc[t] = a;
    }
#pragma unroll
    for (int t = 0; t < 4; ++t)
#pragma unroll
      for (int r = 0; r < 4; ++r)
        pos_s[posw + 16*t + r] = pacc[t][r];

    // ---- cont MFMAs (swapped: A=K rows, D rows = band pos, cols = q-row) ----
    f32x4 cacc[5];
#pragma unroll
    for (int t = 0; t < 5; ++t) {
      f32x4 a = {0.f,0.f,0.f,0.f};
      a = mfma16(kf[t][0], qf0, a);
      a = mfma16(kf[t][1], qf1, a);
      cacc[t] = a;
    }

    // ---- issue next chunk's K/pe (kf/pf regs now dead); pinned ----
    {
      const int l0n = (ch < 15) ? l0 + 64 : l0;
      const int tkn = (m0 + l0n) >> 4;
      const int tpn = l0n >> 4;
#pragma unroll
      for (int t = 0; t < 5; ++t) {
        const bf16* kr = kbF + (size_t)(tkn + t) * 1024;
        kf[t][0] = ld8any(kr); kf[t][1] = ld8any(kr + 512);
      }
#pragma unroll
      for (int t = 0; t < 4; ++t) {
        const bf16* pr = pbF + (size_t)(tpn + t) * 1024;
        pf[t][0] = ld8any(pr); pf[t][1] = ld8any(pr + 512);
      }
      __builtin_amdgcn_sched_barrier(0);
    }

    // ---- per-lane softmax over this row's 64-key window ----
    float sc[5][4];
    float mc = -1.0e30f;
#pragma unroll
    for (int t = 0; t < 5; ++t) {
      const f32x4 pv4 = *reinterpret_cast<const f32x4*>(&pos_s[posr + 16*t]);
#pragma unroll
      for (int r = 0; r < 4; ++r) {
        const float v = fmaf(cacc[t][r] + pv4[r], 0.125f, bias_[t][r]);
        sc[t][r] = v;
        mc = fmaxf(mc, v);
      }
    }
    mc = fmaxf(mc, __shfl_xor(mc, 16));
    mc = fmaxf(mc, __shfl_xor(mc, 32));
    const float Mnew = fmaxf(Mrun, mc);
    const bool defer = __all(Mnew - Mrun <= 8.0f);
    const float Mb = defer ? Mrun : Mnew;      // wave-uniform select
    const float chf = (float)ch * 2.0f;        // l0 * 0.03125
    float ls = 0.0f;
#pragma unroll
    for (int t = 0; t < 5; ++t) {
      short4_ pk;
#pragma unroll
      for (int r = 0; r < 4; ++r) {
        const float p = __expf(sc[t][r] - Mb);  // 0 for masked slots
        ls += p;
        float mv = mvs_[t][r] + chf;
        mv = fminf(fmaxf(mv, 0.0f), 1.0f);
        pk[r] = bf_bits(p * mv);
      }
      *reinterpret_cast<short4_*>(&P_s[pww + 16*t]) = pk;
    }
    ls += __shfl_xor(ls, 16);
    ls += __shfl_xor(ls, 32);

    if (defer) {
      Srun += ls;                 // no rescale, Mrun unchanged
    } else {
      const float alpha = __expf(Mrun - Mnew);
      Srun = Srun * alpha + ls;
      Mrun = Mnew;
#pragma unroll
      for (int dt = 0; dt < 4; ++dt)
#pragma unroll
        for (int r = 0; r < 4; ++r) o[dt][r] *= alpha;
    }

    // ---- PV (swapped: A=V^T rows=d, B=P cols=q-row) ----
#pragma unroll
    for (int ks = 0; ks < 3; ++ks) {
      const bf16x8 ap = ld8any(&P_s[pwr + ks*32]);
#pragma unroll
      for (int dt = 0; dt < 4; ++dt)
        o[dt] = mfma16(vf[dt][ks], ap, o[dt]);
    }

    // ---- issue next chunk's V (vf regs now dead); pinned ----
    {
      const int tkn = (m0 + ((ch < 15) ? l0 + 64 : l0)) >> 4;
#pragma unroll
      for (int dt = 0; dt < 4; ++dt) {
        const bf16* v0 = vbF + (size_t)dt * 24576 + (size_t)tkn * 256;
#pragma unroll
        for (int ks = 0; ks < 3; ++ks) vf[dt][ks] = ld8any(v0 + ks*512);
      }
      __builtin_amdgcn_sched_barrier(0);
    }
  }

  // ---- epilogue: lane-local normalize, fragment-linear ctx stores ----
  const float inv = 1.0f / Srun;
  bf16* crb = ctx + (size_t)((b*SM + m0) >> 4) * 8192
            + (size_t)(h*1024 + (quad>>1)*128 + col16*8 + (quad&1)*4);
#pragma unroll
  for (int dt = 0; dt < 4; ++dt) {
    short4_ pk;
#pragma unroll
    for (int r = 0; r < 4; ++r) pk[r] = bf_bits(o[dt][r] * inv);
    *reinterpret_cast<short4_*>(crb + (size_t)(dt>>1)*512 + (dt&1)*256) = pk;
  }
}

// ---------------------------------------------------------------------------
// Fallback path kernels (round-6 proven, old row-major layouts).
// ---------------------------------------------------------------------------
template <int MODE, typename TX, typename TW, typename TY>
__global__ __launch_bounds__(256) void gemmbn64(const TX* __restrict__ X,
                                                const TW* __restrict__ W,
                                                TY* __restrict__ Y) {
  __shared__ __align__(16) bf16 tile[(MODE == 2) ? 64 * T2STR : 8];
  const int id   = blockIdx.x;
  const int s_   = id >> 3;
  const int xblk = (id & 7) + 8 * (s_ >> 3);
  const int yblk = s_ & 7;
  const int tid  = threadIdx.x;
  const int lane = tid & 63, w = tid >> 6;
  const int col16 = lane & 15, quad = lane >> 4, kq = quad << 3;
  const int wm = w >> 1, wn = w & 1;
  const int m0 = xblk * 128 + wm * 64;
  const int n0 = yblk * 64 + wn * 32;
  const TX* xr = X + (size_t)(m0 + col16) * SH + kq;
  const TW* wr = W + (size_t)(n0 + col16) * SH + kq;
  f32x4 acc[4][2];
#pragma unroll
  for (int i = 0; i < 4; ++i)
#pragma unroll
    for (int j = 0; j < 2; ++j) acc[i][j] = f32x4{0.f,0.f,0.f,0.f};
#pragma unroll
  for (int k0 = 0; k0 < SH; k0 += 32) {
    bf16x8 af[4], bfr[2];
#pragma unroll
    for (int t = 0; t < 4; ++t) af[t]  = ld8any(xr + (size_t)(t*16) * SH + k0);
#pragma unroll
    for (int t = 0; t < 2; ++t) bfr[t] = ld8any(wr + (size_t)(t*16) * SH + k0);
#pragma unroll
    for (int mt = 0; mt < 4; ++mt)
#pragma unroll
      for (int nt = 0; nt < 2; ++nt)
        acc[mt][nt] = mfma16(af[mt], bfr[nt], acc[mt][nt]);
  }

  if constexpr (MODE == 0) {
#pragma unroll
    for (int mt = 0; mt < 4; ++mt)
#pragma unroll
      for (int r = 0; r < 4; ++r) {
        const int row = m0 + mt*16 + quad*4 + r;
        TY* yr = Y + (size_t)row * SH + n0 + col16;
        st1(yr,      acc[mt][0][r]);
        st1(yr + 16, acc[mt][1][r]);
      }
  } else if constexpr (MODE == 1) {
#pragma unroll
    for (int mt = 0; mt < 4; ++mt)
#pragma unroll
      for (int r = 0; r < 4; ++r) {
        const int row = m0 + mt*16 + quad*4 + r;
        const int b = row / SN, sr = row - b * SN;
        bf16* yr = (bf16*)Y + (size_t)((b*NH + yblk)*SN + sr) * HD
                 + wn*32 + col16;
        yr[0]  = __float2bfloat16(acc[mt][0][r]);
        yr[16] = __float2bfloat16(acc[mt][1][r]);
      }
  } else {
#pragma unroll
    for (int mt = 0; mt < 4; ++mt)
#pragma unroll
      for (int r = 0; r < 4; ++r) {
        const int row_loc = wm*64 + mt*16 + quad*4 + r;
#pragma unroll
        for (int nt = 0; nt < 2; ++nt) {
          const int d = wn*32 + nt*16 + col16;
          tile[d * T2STR + row_loc] = __float2bfloat16(acc[mt][nt][r]);
        }
      }
    __syncthreads();
    const int d  = tid >> 2;
    const int hq = tid & 3;
    const bf16* src = tile + d * T2STR + hq * 32;
    const int row0 = xblk*128 + hq*32;
    const int b = row0 / SN, sr0 = row0 - b * SN;
    bf16* dst = (bf16*)Y + (size_t)((b*NH + yblk)*HD + d) * SN + sr0;
#pragma unroll
    for (int i = 0; i < 4; ++i)
      reinterpret_cast<uint4*>(dst)[i] = reinterpret_cast<const uint4*>(src)[i];
  }
}

__global__ void transpose_pe_fb(const float* __restrict__ pe, bf16* __restrict__ peT) {
  int idx = blockIdx.x * 256 + threadIdx.x;
  int l = idx >> 6, d = idx & 63;
  peT[idx] = __float2bfloat16(pe[d * SL + l]);
}

#define MT 16
#define CSTR 84
#define PSTR 65
#define BSTR 104
#define QSTR 72

__global__ __launch_bounds__(128) void attn_kernel_fb(
    const float* __restrict__ query, const float* __restrict__ Wq,
    const bf16* __restrict__ Kh, const bf16* __restrict__ VT,
    const bf16* __restrict__ peT, const float* __restrict__ spanv,
    bf16* __restrict__ ctx) {
  __shared__ __align__(16) float cont_lds[MT][CSTR];
  __shared__ __align__(16) float pos_lds[MT][PSTR];
  __shared__ __align__(16) bf16  P_lds[MT][BSTR];
  __shared__ __align__(16) bf16  q_lds[MT*QSTR];
  __shared__ float alpha_lds[MT];
  __shared__ float S_lds[MT];

  const int id = blockIdx.x;
  const int h  = id & 7;
  const int s_ = id >> 3;
  const int m0 = (s_ & 31) * MT;
  const int b  = s_ >> 5;
  const int hb = b * 8 + h;
  const int tid  = threadIdx.x;
  const int lane = tid & 63;
  const int w    = tid >> 6;
  const int col16 = lane & 15, quad = lane >> 4, kq = quad << 3;
  const int wr = quad << 2;

  for (int i = tid; i < MT * BSTR; i += 128)
    (&P_lds[0][0])[i] = __float2bfloat16(0.0f);

  bf16x8 qf0, qf1;
  {
    f32x4 qa0 = {0.f,0.f,0.f,0.f}, qa1 = qa0;
    const float* xq = query + (size_t)(b*SM + m0 + col16) * SH + kq;
    const float* w0 = Wq + (size_t)(h*HD + w*32 + col16) * SH + kq;
    const float* w1 = w0 + (size_t)16 * SH;
#pragma unroll
    for (int k0 = 0; k0 < SH; k0 += 32) {
      bf16x8 xa = ld8any(xq + k0);
      qa0 = mfma16(xa, ld8any(w0 + k0), qa0);
      qa1 = mfma16(xa, ld8any(w1 + k0), qa1);
    }
#pragma unroll
    for (int r = 0; r < 4; ++r) {
      q_lds[(wr + r)*QSTR + w*32 + col16]      = __float2bfloat16(qa0[r]);
      q_lds[(wr + r)*QSTR + w*32 + 16 + col16] = __float2bfloat16(qa1[r]);
    }
    __syncthreads();
    qf0 = ld8any(&q_lds[col16*QSTR + kq]);
    qf1 = ld8any(&q_lds[col16*QSTR + kq + 32]);
  }

  const bf16* kb = Kh + (size_t)(hb * SN) * HD + kq;
  const bf16* vb = VT + (size_t)(hb * HD) * SN;

  const int srow = tid >> 3, sj = tid & 7;
  float Mrun = -1.0e30f, Srun = 0.0f;
  const float span = spanv[h];
  const int dt0 = w * 16, dt1 = (w + 2) * 16;
  f32x4 o0 = {0.f,0.f,0.f,0.f}, o1 = o0;

  for (int ch = 0; ch < 16; ++ch) {
    const int l0 = ch << 6;
    const int nb_ = m0 + l0;

    f32x4 ca0 = {0.f,0.f,0.f,0.f}, ca1 = ca0, ca2 = ca0, pa0 = ca0, pa1 = ca0;
    {
      const bf16* kr0 = kb + (size_t)(nb_ + w*16 + col16) * HD;
      ca0 = mfma16(qf0, ld8any(kr0),           ca0);
      ca0 = mfma16(qf1, ld8any(kr0 + 32),      ca0);
      const bf16* kr1 = kr0 + 32 * HD;
      ca1 = mfma16(qf0, ld8any(kr1),           ca1);
      ca1 = mfma16(qf1, ld8any(kr1 + 32),      ca1);
      if (w == 0) {
        const bf16* kr2 = kr0 + 64 * HD;
        ca2 = mfma16(qf0, ld8any(kr2),         ca2);
        ca2 = mfma16(qf1, ld8any(kr2 + 32),    ca2);
      }
      const bf16* pr0 = peT + (size_t)(l0 + w*16 + col16) * HD + kq;
      pa0 = mfma16(qf0, ld8any(pr0),           pa0);
      pa0 = mfma16(qf1, ld8any(pr0 + 32),      pa0);
      const bf16* pr1 = pr0 + 32 * HD;
      pa1 = mfma16(qf0, ld8any(pr1),           pa1);
      pa1 = mfma16(qf1, ld8any(pr1 + 32),      pa1);
    }
#pragma unroll
    for (int r = 0; r < 4; ++r) {
      cont_lds[wr + r][w*16 + col16]      = ca0[r];
      cont_lds[wr + r][w*16 + 32 + col16] = ca1[r];
      if (w == 0) cont_lds[wr + r][64 + col16] = ca2[r];
      pos_lds[wr + r][w*16 + col16]       = pa0[r];
      pos_lds[wr + r][w*16 + 32 + col16]  = pa1[r];
    }
    __syncthreads();

    float sc[8];
    float mc = -1.0e30f;
    const float* crow = &cont_lds[srow][srow + sj*8];
    const float* prow = &pos_lds[srow][sj*8];
#pragma unroll
    for (int i = 0; i < 8; ++i) {
      float v = (crow[i] + prow[i]) * 0.125f;
      sc[i] = v;
      mc = fmaxf(mc, v);
    }
    mc = fmaxf(mc, __shfl_xor(mc, 1));
    mc = fmaxf(mc, __shfl_xor(mc, 2));
    mc = fmaxf(mc, __shfl_xor(mc, 4));
    const float Mnew = fmaxf(Mrun, mc);
    const float alpha = __expf(Mrun - Mnew);
    float ls = 0.0f;
    bf16* pwrow = &P_lds[srow][srow + sj*8];
#pragma unroll
    for (int i = 0; i < 8; ++i) {
      float p = __expf(sc[i] - Mnew);
      ls += p;
      const float tpl = (float)(l0 + sj*8 + i) - 1023.0f;
      float mv = (tpl + span * 1024.0f) * 0.03125f + 1.0f;
      mv = fminf(fmaxf(mv, 0.0f), 1.0f);
      pwrow[i] = __float2bfloat16(p * mv);
    }
    ls += __shfl_xor(ls, 1);
    ls += __shfl_xor(ls, 2);
    ls += __shfl_xor(ls, 4);
    Srun = Srun * alpha + ls;
    Mrun = Mnew;
    if (sj == 0) { alpha_lds[srow] = alpha; S_lds[srow] = Srun; }
    __syncthreads();

    float al[4];
#pragma unroll
    for (int r = 0; r < 4; ++r) al[r] = alpha_lds[wr + r];
#pragma unroll
    for (int r = 0; r < 4; ++r) { o0[r] *= al[r]; o1[r] *= al[r]; }
#pragma unroll
    for (int ks = 0; ks < 3; ++ks) {
      const bf16x8 ap = ld8any(&P_lds[col16][ks*32 + kq]);
      const bf16* v0 = vb + (size_t)(dt0 + col16) * SN + nb_ + ks*32 + kq;
      const bf16* v1 = vb + (size_t)(dt1 + col16) * SN + nb_ + ks*32 + kq;
      o0 = mfma16(ap, ld8any(v0), o0);
      o1 = mfma16(ap, ld8any(v1), o1);
    }
  }

  bf16* cr = ctx + (size_t)(b*SM + m0 + wr) * SH + h*HD + col16;
#pragma unroll
  for (int r = 0; r < 4; ++r) {
    const float inv = 1.0f / S_lds[wr + r];
    cr[(size_t)r * SH + dt0] = __float2bfloat16(o0[r] * inv);
    cr[(size_t)r * SH + dt1] = __float2bfloat16(o1[r] * inv);
  }
}

// ---------------------------------------------------------------------------
extern "C" void kernel_launch(void* const* d_in, const int* in_sizes, int n_in,
                              void* d_out, int out_size, void* d_ws, size_t ws_size,
                              hipStream_t stream) {
  const float* query  = (const float*)d_in[0];
  const float* key    = (const float*)d_in[1];
  const float* value  = (const float*)d_in[2];
  const float* key_pe = (const float*)d_in[3];
  const float* Wq     = (const float*)d_in[4];
  const float* Wk     = (const float*)d_in[5];
  const float* Wv     = (const float*)d_in[6];
  const float* Wo     = (const float*)d_in[7];
  const float* spanv  = (const float*)d_in[8];
  float* out = (float*)d_out;

  bf16* ws = (bf16*)d_ws;
  if (ws_size >= (size_t)48365568) {
    // Path C: fused-conversion fragment-linear pipeline, 4 launches.
    bf16* B0   = ws;                      // vF
    bf16* B1   = B0  + 6291456;           // (unused; layout kept)
    bf16* B2   = B1  + 6291456;           // kF
    bf16* qp   = B2  + 6291456;           // qpF
    bf16* ctxC = qp  + 2097152;           // attn ctx (fragment-linear)
    bf16* peF  = ctxC + 2097152;
    bf16* Wb   = peF + 65536;
    bf16* Wq_b = Wb, *Wk_b = Wb + 262144, *Wv_b = Wb + 524288, *Wo_b = Wb + 786432;

    // L1: weights + pe (pe now FULLY written — rounds 9-10 covered 1/8).
    prep_small<<<384, 256, 0, stream>>>(Wq, Wk, Wv, Wo, key_pe, Wb, peF);
    // L2: K+Q+V projections, f32 inputs converted in-kernel via LDS staging.
    gemmKQV<<<896, 256, 0, stream>>>(key, query, value, Wk_b, Wq_b, Wv_b,
                                     B2, qp, B0);
    // L3: fused attention.
    attn1w<<<2048, 64, 0, stream>>>(qp, B2, B0, peF, spanv, ctxC);
    // L4: output projection.
    gemmO<<<256, 256, 0, stream>>>(ctxC, Wo_b, out);
  } else {
    // Path B (fallback): fused-q attention, f32 GEMM reads, 29.5 MB ws.
    bf16* k_head = ws;
    bf16* vT     = k_head + 6291456;
    bf16* ctx    = vT     + 6291456;
    bf16* peT    = ctx    + 2097152;
    gemmbn64<1, float, float, bf16><<<768, 256, 0, stream>>>(key,   Wk, k_head);
    gemmbn64<2, float, float, bf16><<<768, 256, 0, stream>>>(value, Wv, vT);
    transpose_pe_fb<<<256, 256, 0, stream>>>(key_pe, peT);
    attn_kernel_fb<<<2048, 128, 0, stream>>>(query, Wq, k_head, vT,
                                             peT, spanv, ctx);
    gemmbn64<0, bf16, float, float><<<256, 256, 0, stream>>>(ctx, Wo, out);
  }
}

// Round 12
// 187.910 us; speedup vs baseline: 1.0203x; 1.0203x over previous
//
#include <hip/hip_runtime.h>
#include <hip/hip_bf16.h>
#include <type_traits>

typedef __hip_bfloat16 bf16;
typedef short bf16x8 __attribute__((ext_vector_type(8)));
typedef float f32x4 __attribute__((ext_vector_type(4)));
typedef short short4_ __attribute__((ext_vector_type(4)));

#define NB 8      // batch
#define SM 512    // block size M
#define SL 1024   // attn span L
#define SH 512    // hidden
#define NH 8      // heads
#define HD 64     // head dim
#define SN 1536   // M + L (key length)

static __device__ __forceinline__ short bf_bits(float x) {
  union { bf16 b; short s; } u; u.b = __float2bfloat16(x); return u.s;
}
static __device__ __forceinline__ bf16x8 ld8any(const bf16* p) {
  return *reinterpret_cast<const bf16x8*>(p);
}
static __device__ __forceinline__ bf16x8 ld8any(const float* p) {
  float4 a = *reinterpret_cast<const float4*>(p);
  float4 b = *reinterpret_cast<const float4*>(p + 4);
  bf16x8 r;
  r[0] = bf_bits(a.x); r[1] = bf_bits(a.y); r[2] = bf_bits(a.z); r[3] = bf_bits(a.w);
  r[4] = bf_bits(b.x); r[5] = bf_bits(b.y); r[6] = bf_bits(b.z); r[7] = bf_bits(b.w);
  return r;
}
static __device__ __forceinline__ void st1(bf16* p, float v) { *p = __float2bfloat16(v); }
static __device__ __forceinline__ void st1(float* p, float v) { *p = v; }
static __device__ __forceinline__ f32x4 mfma16(bf16x8 a, bf16x8 b, f32x4 c) {
  return __builtin_amdgcn_mfma_f32_16x16x32_bf16(a, b, c, 0, 0, 0);
}

// ---------------------------------------------------------------------------
// Universal fragment-linear layout for an [R x C] matrix (C = 512):
//   FRAGIDX(row,col) = (row>>4)*8192 + (col>>5)*512
//                    + ((col>>3)&3)*128 + (row&15)*8 + (col&7)
// One wave MFMA fragment (16 rows x 32 cols) = 1KB contiguous, lane*16B.
// ---------------------------------------------------------------------------

// ---------------------------------------------------------------------------
// prep_small: weights + pe only.
// ---------------------------------------------------------------------------
__global__ __launch_bounds__(256) void prep_small(
    const float* __restrict__ Wq, const float* __restrict__ Wk,
    const float* __restrict__ Wv, const float* __restrict__ Wo,
    const float* __restrict__ pe,
    bf16* __restrict__ Wb, bf16* __restrict__ peF) {
  __shared__ __align__(16) bf16 t[16 * 520];
  const int id = blockIdx.x, tid = threadIdx.x;
  if (id < 128) {
    const float* ws_[4] = {Wq, Wk, Wv, Wo};
    const float* src = ws_[id >> 5] + (size_t)(id & 31) * 8192;
    bf16* dst = Wb + (size_t)(id >> 5) * 262144 + (size_t)(id & 31) * 8192;
#pragma unroll
    for (int j = 0; j < 4; ++j) {
      const int i = j * 2048 + tid * 8;
      const bf16x8 v = ld8any(src + i);
      *reinterpret_cast<bf16x8*>(&t[(i >> 9) * 520 + (i & 511)]) = v;
    }
    __syncthreads();
#pragma unroll
    for (int j = 0; j < 4; ++j) {
      const int a = j * 2048 + tid * 8;
      const int kt5 = a >> 9, rest = a & 511;
      const int q = rest >> 7, rowl = (rest >> 3) & 15;
      *reinterpret_cast<bf16x8*>(dst + a) =
          *reinterpret_cast<const bf16x8*>(&t[rowl * 520 + kt5 * 32 + q * 8]);
    }
  } else {
    const int idx = (id - 128) * 256 + tid;   // 0..65535, full peF
    const int l = idx >> 6, d = idx & 63;
    peF[(size_t)((l >> 4) * 2 + (d >> 5)) * 512
        + (size_t)((((d >> 3) & 3) * 16 + (l & 15)) * 8 + (d & 7))]
      = __float2bfloat16(pe[d * SL + l]);
  }
}

// ---------------------------------------------------------------------------
// gemm_f32dev: Y = X @ W^T with X ROW-MAJOR F32 (converted on the fly via
// fragment-linear LDS staging, double-buffered).  W fragment-linear bf16.
// BM=128 x BN=128, 4 waves, wave tile 64x64.
// MODE 1: kF out.  MODE 2: vF out (LDS transpose).  MODE 3: qpF out.
// ---------------------------------------------------------------------------
#define T2STR 136

#define WLOADF(BF, KT)                                                       \
  {                                                                          \
    BF[0] = ld8any(wr +         (size_t)(KT) * 512);                         \
    BF[1] = ld8any(wr + 8192  + (size_t)(KT) * 512);                         \
    BF[2] = ld8any(wr + 16384 + (size_t)(KT) * 512);                         \
    BF[3] = ld8any(wr + 24576 + (size_t)(KT) * 512);                         \
  }

template <int MODE>
static __device__ __forceinline__ void gemm_f32dev(
    const float* __restrict__ X, const bf16* __restrict__ WF,
    bf16* __restrict__ Y, int xblk, int yblk, bf16* lds) {
  const int tid  = threadIdx.x;
  const int lane = tid & 63, w = tid >> 6;
  const int col16 = lane & 15, quad = lane >> 4;
  const int lane8 = lane * 8;
  const int wm = w >> 1, wn = w & 1;
  const int m0 = xblk * 128 + wm * 64;
  const int n0 = yblk * 128 + wn * 64;
  const bf16* wr = WF + (size_t)(n0 >> 4) * 8192 + lane8;

  // staging mapping: j=0..3, row = j*32 + (tid>>3), col = (tid&7)*4
  const int srow_ = tid >> 3, sc_ = (tid & 7) * 4;
  const float* xb = X + (size_t)(xblk * 128) * 512;

  auto xload = [&](int KT, float4* x4) {
#pragma unroll
    for (int j = 0; j < 4; ++j)
      x4[j] = *reinterpret_cast<const float4*>(
          xb + (size_t)(j * 32 + srow_) * 512 + KT * 32 + sc_);
  };
  auto xwrite = [&](int BUF, const float4* x4) {
#pragma unroll
    for (int j = 0; j < 4; ++j) {
      const int row = j * 32 + srow_;
      const int el = BUF * 4096 + (row >> 4) * 512
                   + ((sc_ >> 3) & 3) * 128 + (row & 15) * 8 + (sc_ & 7);
      short4_ pk;
      pk[0] = bf_bits(x4[j].x); pk[1] = bf_bits(x4[j].y);
      pk[2] = bf_bits(x4[j].z); pk[3] = bf_bits(x4[j].w);
      *reinterpret_cast<short4_*>(lds + el) = pk;
    }
  };

  f32x4 acc[4][4];
#pragma unroll
  for (int i = 0; i < 4; ++i)
#pragma unroll
    for (int j = 0; j < 4; ++j) acc[i][j] = f32x4{0.f,0.f,0.f,0.f};

  bf16x8 wA[4], wB[4];
  {
    float4 xc[4];
    xload(0, xc);
    WLOADF(wA, 0);
    __builtin_amdgcn_sched_barrier(0);
    xwrite(0, xc);
  }
  __syncthreads();

#pragma unroll
  for (int kt = 0; kt < 16; ++kt) {
    float4 xn[4];
    if (kt < 15) {
      xload(kt + 1, xn);
      if (kt & 1) { WLOADF(wA, kt + 1); } else { WLOADF(wB, kt + 1); }
      __builtin_amdgcn_sched_barrier(0);
    }
    bf16x8 af[4];
#pragma unroll
    for (int t = 0; t < 4; ++t)
      af[t] = ld8any(lds + (kt & 1) * 4096 + (wm * 4 + t) * 512 + lane8);
#pragma unroll
    for (int mt = 0; mt < 4; ++mt)
#pragma unroll
      for (int nt = 0; nt < 4; ++nt)
        acc[mt][nt] = mfma16(af[mt], (kt & 1) ? wB[nt] : wA[nt], acc[mt][nt]);
    if (kt < 15) xwrite((kt + 1) & 1, xn);
    __syncthreads();
  }

  if constexpr (MODE == 1) {
    // kF: head h = n0>>6; within-half idx = key8 + q*128 + de.
    const int dq = col16 >> 3, de = col16 & 7;
    const int head = n0 >> 6;
#pragma unroll
    for (int mt = 0; mt < 4; ++mt)
#pragma unroll
      for (int r = 0; r < 4; ++r) {
        const int row = m0 + mt*16 + quad*4 + r;
        const int b = row / SN, sr = row - b * SN;
        bf16* yr = (bf16*)Y
            + (((size_t)(b*NH + head)*96 + (sr>>4))*2)*512
            + (size_t)((sr&15)*8 + de);
#pragma unroll
        for (int nt = 0; nt < 4; ++nt)
          yr[(nt>>1)*512 + ((nt&1)*2 + dq)*128] = __float2bfloat16(acc[mt][nt][r]);
      }
  } else if constexpr (MODE == 3) {
    const int dq = col16 >> 3, de = col16 & 7;
    const int c5b = n0 >> 5;
#pragma unroll
    for (int mt = 0; mt < 4; ++mt)
#pragma unroll
      for (int r = 0; r < 4; ++r) {
        bf16* yr = (bf16*)Y + (size_t)((m0>>4) + mt) * 8192
                 + (size_t)((quad*4 + r)*8 + de);
#pragma unroll
        for (int nt = 0; nt < 4; ++nt)
          yr[(c5b + (nt>>1))*512 + ((nt&1)*2 + dq)*128] = __float2bfloat16(acc[mt][nt][r]);
      }
  } else {
    // vF via LDS transpose: lds[d 0..127][row_loc 0..127] (post-loop reuse)
    bf16* tile = lds;
#pragma unroll
    for (int mt = 0; mt < 4; ++mt)
#pragma unroll
      for (int r = 0; r < 4; ++r) {
        const int row_loc = wm*64 + mt*16 + quad*4 + r;
#pragma unroll
        for (int nt = 0; nt < 4; ++nt) {
          const int d = wn*64 + nt*16 + col16;
          tile[d * T2STR + row_loc] = __float2bfloat16(acc[mt][nt][r]);
        }
      }
    __syncthreads();
    const int d  = tid >> 1;      // 0..127
    const int hq = tid & 1;       // 64-row half
    const bf16* src = tile + d * T2STR + hq * 64;
    const int row0 = xblk*128 + hq*64;
    const int b = row0 / SN, sr0 = row0 - b * SN;
    const int head = yblk*2 + (d >> 6);
    const int dd = d & 63;
    bf16* dstF = (bf16*)Y + (((size_t)(b*NH + head)*4 + (dd>>4))*96)*256
               + (size_t)(dd&15)*8;
#pragma unroll
    for (int i = 0; i < 8; ++i) {
      const int key = sr0 + i*8;
      const size_t off = (size_t)(key>>4)*256 + (size_t)((key>>3)&1)*128;
      *reinterpret_cast<uint4*>(dstF + off) = reinterpret_cast<const uint4*>(src)[i];
    }
  }
}

// Merged K+Q+V projection, ONE launch. v12: XCD-aware block remap.
// Blocks with equal (id mod 8) dispatch to the same XCD; within each
// 32-block supergroup assign xblk = g*8 + (lid&7), yblk = (lid>>3)&3 so the
// FOUR blocks sharing an X panel (same xblk, yblk 0..3) are spaced 8 apart
// -> same XCD -> the f32 X panel is fetched from HBM ONCE per XCD-L2
// (round-11 mapping put them on 4 different XCDs: FETCH 116 MB, 2x unique).
//  [0,384):   K-proj  key f32   -> kF  (B2)
//  [384,512): Q-proj  query f32 -> qpF (qp)
//  [512,896): V-proj  value f32 -> vF  (B0)
__global__ __launch_bounds__(256, 2) void gemmKQV(
    const float* __restrict__ key, const float* __restrict__ query,
    const float* __restrict__ value,
    const bf16* __restrict__ Wk_b, const bf16* __restrict__ Wq_b,
    const bf16* __restrict__ Wv_b,
    bf16* __restrict__ kF, bf16* __restrict__ qpF, bf16* __restrict__ vF) {
  __shared__ __align__(16) bf16 lds[128 * T2STR];  // 34.8KB (union w/ staging)
  const int id = blockIdx.x;
  int lid, mode;
  const float* X; const bf16* W; bf16* Y;
  if (id < 384)      { lid = id;       mode = 1; X = key;   W = Wk_b; Y = kF;  }
  else if (id < 512) { lid = id - 384; mode = 3; X = query; W = Wq_b; Y = qpF; }
  else               { lid = id - 512; mode = 2; X = value; W = Wv_b; Y = vF;  }
  // segment offsets (384, 512) are multiples of 32 -> lid mod 8 == id mod 8,
  // so the same-XCD grouping holds within every segment.
  const int g    = lid >> 5;
  const int xblk = g * 8 + (lid & 7);
  const int yblk = (lid >> 3) & 3;
  if (mode == 1)      gemm_f32dev<1>(X, W, Y, xblk, yblk, lds);
  else if (mode == 3) gemm_f32dev<3>(X, W, Y, xblk, yblk, lds);
  else                gemm_f32dev<2>(X, W, Y, xblk, yblk, lds);
}

// ---------------------------------------------------------------------------
// gemmO: 64x32 wave tile (BM=128, BN=64), grid 256 -> full-GPU coverage.
// ---------------------------------------------------------------------------
#define GLO(AF, BF, KT)                                                      \
  {                                                                          \
    AF[0] = ld8any(xr +         (size_t)(KT) * 512);                         \
    AF[1] = ld8any(xr + 8192  + (size_t)(KT) * 512);                         \
    AF[2] = ld8any(xr + 16384 + (size_t)(KT) * 512);                         \
    AF[3] = ld8any(xr + 24576 + (size_t)(KT) * 512);                         \
    BF[0] = ld8any(wr +         (size_t)(KT) * 512);                         \
    BF[1] = ld8any(wr + 8192  + (size_t)(KT) * 512);                         \
  }

__global__ __launch_bounds__(256, 2) void gemmO(
    const bf16* __restrict__ XF, const bf16* __restrict__ WF, float* __restrict__ Y) {
  const int id   = blockIdx.x;
  const int s_   = id >> 3;
  const int xblk = (id & 7) + 8 * (s_ >> 3);
  const int yblk = s_ & 7;
  const int tid  = threadIdx.x;
  const int lane = tid & 63, w = tid >> 6;
  const int col16 = lane & 15, quad = lane >> 4;
  const int lane8 = lane * 8;
  const int wm = w >> 1, wn = w & 1;
  const int m0 = xblk * 128 + wm * 64;
  const int n0 = yblk * 64 + wn * 32;
  const bf16* xr = XF + (size_t)(m0 >> 4) * 8192 + lane8;
  const bf16* wr = WF + (size_t)(n0 >> 4) * 8192 + lane8;
  f32x4 acc[4][2];
#pragma unroll
  for (int i = 0; i < 4; ++i)
#pragma unroll
    for (int j = 0; j < 2; ++j) acc[i][j] = f32x4{0.f,0.f,0.f,0.f};

  bf16x8 afA[4], bfA[2], afB[4], bfB[2];
  GLO(afA, bfA, 0);
  __builtin_amdgcn_sched_barrier(0);
#pragma unroll
  for (int kt = 0; kt < 16; kt += 2) {
    GLO(afB, bfB, kt + 1);
    __builtin_amdgcn_sched_barrier(0);
#pragma unroll
    for (int mt = 0; mt < 4; ++mt)
#pragma unroll
      for (int nt = 0; nt < 2; ++nt)
        acc[mt][nt] = mfma16(afA[mt], bfA[nt], acc[mt][nt]);
    const int ktn = (kt + 2 < 16) ? kt + 2 : kt;
    GLO(afA, bfA, ktn);
    __builtin_amdgcn_sched_barrier(0);
#pragma unroll
    for (int mt = 0; mt < 4; ++mt)
#pragma unroll
      for (int nt = 0; nt < 2; ++nt)
        acc[mt][nt] = mfma16(afB[mt], bfB[nt], acc[mt][nt]);
  }
#pragma unroll
  for (int mt = 0; mt < 4; ++mt)
#pragma unroll
    for (int r = 0; r < 4; ++r) {
      const int row = m0 + mt*16 + quad*4 + r;
      float* yr = Y + (size_t)row * SH + n0 + col16;
      yr[0]  = acc[mt][0][r];
      yr[16] = acc[mt][1][r];
    }
}

// ---------------------------------------------------------------------------
// Barrier-free wave-private fused attention (round-10 proven, ~45 us).
// ---------------------------------------------------------------------------
#define PSTR1 69    // pos stride (f32): scalar writes, b128-aligned reads
#define BSTR1 104   // P stride (bf16): b64 writes, b128 reads aligned

__global__ __launch_bounds__(64, 2) void attn1w(
    const bf16* __restrict__ qp, const bf16* __restrict__ Kh,
    const bf16* __restrict__ VT, const bf16* __restrict__ peT,
    const float* __restrict__ spanv, bf16* __restrict__ ctx) {
  __shared__ __align__(16) float pos_s[16 * PSTR1];
  __shared__ __align__(16) bf16  P_s[16 * BSTR1];

  const int id = blockIdx.x;
  const int h  = id & 7;
  const int s_ = id >> 3;
  const int m0 = (s_ & 31) * 16;
  const int b  = s_ >> 5;
  const int hb = b * 8 + h;
  const int lane  = threadIdx.x;
  const int col16 = lane & 15, quad = lane >> 4, kq = quad << 3;
  const int q4 = quad << 2;
  const int lane8 = lane * 8;

  // zero P band once (cols 80..103 stay zero; read by ks=2 PV fragment)
  for (int i = lane; i < 16 * BSTR1; i += 64)
    P_s[i] = __float2bfloat16(0.0f);

  // q from fragment-linear qp: rt*8192 + h*1024 + lane*8 (and +512)
  const bf16* qb = qp + (size_t)((b*SM + m0) >> 4) * 8192 + h*1024 + lane8;
  const bf16x8 qf0 = ld8any(qb), qf1 = ld8any(qb + 512);

  const bf16* kbF = Kh + (size_t)hb * 98304 + lane8;   // 96 tiles * 1024
  const bf16* vbF = VT + (size_t)hb * 98304 + lane8;   // 4 dt * 96 kt * 256
  const bf16* pbF = peT + lane8;

  float Mrun = -1.0e30f, Srun = 0.0f;
  const float span1024 = spanv[h] * 1024.0f;
  f32x4 o[4];
#pragma unroll
  for (int dt = 0; dt < 4; ++dt) o[dt] = f32x4{0.f,0.f,0.f,0.f};

  // loop-invariant per-lane softmax constants
  float bias_[5][4], mvs_[5][4];
  {
    const float mvb = ((float)(q4 - col16 - 1023) + span1024) * 0.03125f + 1.0f;
#pragma unroll
    for (int t = 0; t < 5; ++t)
#pragma unroll
      for (int r = 0; r < 4; ++r) {
        const int l = 16*t + q4 + r - col16;
        bias_[t][r] = ((unsigned)l < 64u) ? 0.0f : -1.0e30f;
        mvs_[t][r]  = mvb + (float)(16*t + r) * 0.03125f;
      }
  }

  // prefetched operand fragments (single-buffered; WAR ordering via reg deps)
  bf16x8 kf[5][2], pf[4][2], vf[4][3];

  // ---- prologue: chunk-0 operands ----
  {
    const int tk0 = m0 >> 4;
#pragma unroll
    for (int t = 0; t < 5; ++t) {
      const bf16* kr = kbF + (size_t)(tk0 + t) * 1024;
      kf[t][0] = ld8any(kr); kf[t][1] = ld8any(kr + 512);
    }
#pragma unroll
    for (int t = 0; t < 4; ++t) {
      const bf16* pr = pbF + (size_t)t * 1024;
      pf[t][0] = ld8any(pr); pf[t][1] = ld8any(pr + 512);
    }
#pragma unroll
    for (int dt = 0; dt < 4; ++dt) {
      const bf16* v0 = vbF + (size_t)dt * 24576 + (size_t)tk0 * 256;
#pragma unroll
      for (int ks = 0; ks < 3; ++ks) vf[dt][ks] = ld8any(v0 + ks*512);
    }
    __builtin_amdgcn_sched_barrier(0);
  }

  const int posw = col16 * PSTR1 + q4;        // write base (scalar f32)
  const int posr = col16 * (PSTR1 - 1) + q4;  // read base (b128-aligned)
  const int pww  = col16 * BSTR1 + q4;        // P write base (b64-aligned)
  const int pwr  = col16 * BSTR1 + kq;        // P read base (b128-aligned)

  for (int ch = 0; ch < 16; ++ch) {
    const int l0 = ch << 6;

    // ---- pos MFMAs (swapped: A=pe rows, D rows = l, cols = q-row) ----
    f32x4 pacc[4];
#pragma unroll
    for (int t = 0; t < 4; ++t) {
      f32x4 a = {0.f,0.f,0.f,0.f};
      a = mfma16(pf[t][0], qf0, a);
      a = mfma16(pf[t][1], qf1, a);
      pacc[t] = a;
    }
#pragma unroll
    for (int t = 0; t < 4; ++t)
#pragma unroll
      for (int r = 0; r < 4; ++r)
        pos_s[posw + 16*t + r] = pacc[t][r];

    // ---- cont MFMAs (swapped: A=K rows, D rows = band pos, cols = q-row) ----
    f32x4 cacc[5];
#pragma unroll
    for (int t = 0; t < 5; ++t) {
      f32x4 a = {0.f,0.f,0.f,0.f};
      a = mfma16(kf[t][0], qf0, a);
      a = mfma16(kf[t][1], qf1, a);
      cacc[t] = a;
    }

    // ---- issue next chunk's K/pe (kf/pf regs now dead); pinned ----
    {
      const int l0n = (ch < 15) ? l0 + 64 : l0;
      const int tkn = (m0 + l0n) >> 4;
      const int tpn = l0n >> 4;
#pragma unroll
      for (int t = 0; t < 5; ++t) {
        const bf16* kr = kbF + (size_t)(tkn + t) * 1024;
        kf[t][0] = ld8any(kr); kf[t][1] = ld8any(kr + 512);
      }
#pragma unroll
      for (int t = 0; t < 4; ++t) {
        const bf16* pr = pbF + (size_t)(tpn + t) * 1024;
        pf[t][0] = ld8any(pr); pf[t][1] = ld8any(pr + 512);
      }
      __builtin_amdgcn_sched_barrier(0);
    }

    // ---- per-lane softmax over this row's 64-key window ----
    float sc[5][4];
    float mc = -1.0e30f;
#pragma unroll
    for (int t = 0; t < 5; ++t) {
      const f32x4 pv4 = *reinterpret_cast<const f32x4*>(&pos_s[posr + 16*t]);
#pragma unroll
      for (int r = 0; r < 4; ++r) {
        const float v = fmaf(cacc[t][r] + pv4[r], 0.125f, bias_[t][r]);
        sc[t][r] = v;
        mc = fmaxf(mc, v);
      }
    }
    mc = fmaxf(mc, __shfl_xor(mc, 16));
    mc = fmaxf(mc, __shfl_xor(mc, 32));
    const float Mnew = fmaxf(Mrun, mc);
    const bool defer = __all(Mnew - Mrun <= 8.0f);
    const float Mb = defer ? Mrun : Mnew;      // wave-uniform select
    const float chf = (float)ch * 2.0f;        // l0 * 0.03125
    float ls = 0.0f;
#pragma unroll
    for (int t = 0; t < 5; ++t) {
      short4_ pk;
#pragma unroll
      for (int r = 0; r < 4; ++r) {
        const float p = __expf(sc[t][r] - Mb);  // 0 for masked slots
        ls += p;
        float mv = mvs_[t][r] + chf;
        mv = fminf(fmaxf(mv, 0.0f), 1.0f);
        pk[r] = bf_bits(p * mv);
      }
      *reinterpret_cast<short4_*>(&P_s[pww + 16*t]) = pk;
    }
    ls += __shfl_xor(ls, 16);
    ls += __shfl_xor(ls, 32);

    if (defer) {
      Srun += ls;                 // no rescale, Mrun unchanged
    } else {
      const float alpha = __expf(Mrun - Mnew);
      Srun = Srun * alpha + ls;
      Mrun = Mnew;
#pragma unroll
      for (int dt = 0; dt < 4; ++dt)
#pragma unroll
        for (int r = 0; r < 4; ++r) o[dt][r] *= alpha;
    }

    // ---- PV (swapped: A=V^T rows=d, B=P cols=q-row) ----
#pragma unroll
    for (int ks = 0; ks < 3; ++ks) {
      const bf16x8 ap = ld8any(&P_s[pwr + ks*32]);
#pragma unroll
      for (int dt = 0; dt < 4; ++dt)
        o[dt] = mfma16(vf[dt][ks], ap, o[dt]);
    }

    // ---- issue next chunk's V (vf regs now dead); pinned ----
    {
      const int tkn = (m0 + ((ch < 15) ? l0 + 64 : l0)) >> 4;
#pragma unroll
      for (int dt = 0; dt < 4; ++dt) {
        const bf16* v0 = vbF + (size_t)dt * 24576 + (size_t)tkn * 256;
#pragma unroll
        for (int ks = 0; ks < 3; ++ks) vf[dt][ks] = ld8any(v0 + ks*512);
      }
      __builtin_amdgcn_sched_barrier(0);
    }
  }

  // ---- epilogue: lane-local normalize, fragment-linear ctx stores ----
  const float inv = 1.0f / Srun;
  bf16* crb = ctx + (size_t)((b*SM + m0) >> 4) * 8192
            + (size_t)(h*1024 + (quad>>1)*128 + col16*8 + (quad&1)*4);
#pragma unroll
  for (int dt = 0; dt < 4; ++dt) {
    short4_ pk;
#pragma unroll
    for (int r = 0; r < 4; ++r) pk[r] = bf_bits(o[dt][r] * inv);
    *reinterpret_cast<short4_*>(crb + (size_t)(dt>>1)*512 + (dt&1)*256) = pk;
  }
}

// ---------------------------------------------------------------------------
// Fallback path kernels (round-6 proven, old row-major layouts).
// ---------------------------------------------------------------------------
template <int MODE, typename TX, typename TW, typename TY>
__global__ __launch_bounds__(256) void gemmbn64(const TX* __restrict__ X,
                                                const TW* __restrict__ W,
                                                TY* __restrict__ Y) {
  __shared__ __align__(16) bf16 tile[(MODE == 2) ? 64 * T2STR : 8];
  const int id   = blockIdx.x;
  const int s_   = id >> 3;
  const int xblk = (id & 7) + 8 * (s_ >> 3);
  const int yblk = s_ & 7;
  const int tid  = threadIdx.x;
  const int lane = tid & 63, w = tid >> 6;
  const int col16 = lane & 15, quad = lane >> 4, kq = quad << 3;
  const int wm = w >> 1, wn = w & 1;
  const int m0 = xblk * 128 + wm * 64;
  const int n0 = yblk * 64 + wn * 32;
  const TX* xr = X + (size_t)(m0 + col16) * SH + kq;
  const TW* wr = W + (size_t)(n0 + col16) * SH + kq;
  f32x4 acc[4][2];
#pragma unroll
  for (int i = 0; i < 4; ++i)
#pragma unroll
    for (int j = 0; j < 2; ++j) acc[i][j] = f32x4{0.f,0.f,0.f,0.f};
#pragma unroll
  for (int k0 = 0; k0 < SH; k0 += 32) {
    bf16x8 af[4], bfr[2];
#pragma unroll
    for (int t = 0; t < 4; ++t) af[t]  = ld8any(xr + (size_t)(t*16) * SH + k0);
#pragma unroll
    for (int t = 0; t < 2; ++t) bfr[t] = ld8any(wr + (size_t)(t*16) * SH + k0);
#pragma unroll
    for (int mt = 0; mt < 4; ++mt)
#pragma unroll
      for (int nt = 0; nt < 2; ++nt)
        acc[mt][nt] = mfma16(af[mt], bfr[nt], acc[mt][nt]);
  }

  if constexpr (MODE == 0) {
#pragma unroll
    for (int mt = 0; mt < 4; ++mt)
#pragma unroll
      for (int r = 0; r < 4; ++r) {
        const int row = m0 + mt*16 + quad*4 + r;
        TY* yr = Y + (size_t)row * SH + n0 + col16;
        st1(yr,      acc[mt][0][r]);
        st1(yr + 16, acc[mt][1][r]);
      }
  } else if constexpr (MODE == 1) {
#pragma unroll
    for (int mt = 0; mt < 4; ++mt)
#pragma unroll
      for (int r = 0; r < 4; ++r) {
        const int row = m0 + mt*16 + quad*4 + r;
        const int b = row / SN, sr = row - b * SN;
        bf16* yr = (bf16*)Y + (size_t)((b*NH + yblk)*SN + sr) * HD
                 + wn*32 + col16;
        yr[0]  = __float2bfloat16(acc[mt][0][r]);
        yr[16] = __float2bfloat16(acc[mt][1][r]);
      }
  } else {
#pragma unroll
    for (int mt = 0; mt < 4; ++mt)
#pragma unroll
      for (int r = 0; r < 4; ++r) {
        const int row_loc = wm*64 + mt*16 + quad*4 + r;
#pragma unroll
        for (int nt = 0; nt < 2; ++nt) {
          const int d = wn*32 + nt*16 + col16;
          tile[d * T2STR + row_loc] = __float2bfloat16(acc[mt][nt][r]);
        }
      }
    __syncthreads();
    const int d  = tid >> 2;
    const int hq = tid & 3;
    const bf16* src = tile + d * T2STR + hq * 32;
    const int row0 = xblk*128 + hq*32;
    const int b = row0 / SN, sr0 = row0 - b * SN;
    bf16* dst = (bf16*)Y + (size_t)((b*NH + yblk)*HD + d) * SN + sr0;
#pragma unroll
    for (int i = 0; i < 4; ++i)
      reinterpret_cast<uint4*>(dst)[i] = reinterpret_cast<const uint4*>(src)[i];
  }
}

__global__ void transpose_pe_fb(const float* __restrict__ pe, bf16* __restrict__ peT) {
  int idx = blockIdx.x * 256 + threadIdx.x;
  int l = idx >> 6, d = idx & 63;
  peT[idx] = __float2bfloat16(pe[d * SL + l]);
}

#define MT 16
#define CSTR 84
#define PSTR 65
#define BSTR 104
#define QSTR 72

__global__ __launch_bounds__(128) void attn_kernel_fb(
    const float* __restrict__ query, const float* __restrict__ Wq,
    const bf16* __restrict__ Kh, const bf16* __restrict__ VT,
    const bf16* __restrict__ peT, const float* __restrict__ spanv,
    bf16* __restrict__ ctx) {
  __shared__ __align__(16) float cont_lds[MT][CSTR];
  __shared__ __align__(16) float pos_lds[MT][PSTR];
  __shared__ __align__(16) bf16  P_lds[MT][BSTR];
  __shared__ __align__(16) bf16  q_lds[MT*QSTR];
  __shared__ float alpha_lds[MT];
  __shared__ float S_lds[MT];

  const int id = blockIdx.x;
  const int h  = id & 7;
  const int s_ = id >> 3;
  const int m0 = (s_ & 31) * MT;
  const int b  = s_ >> 5;
  const int hb = b * 8 + h;
  const int tid  = threadIdx.x;
  const int lane = tid & 63;
  const int w    = tid >> 6;
  const int col16 = lane & 15, quad = lane >> 4, kq = quad << 3;
  const int wr = quad << 2;

  for (int i = tid; i < MT * BSTR; i += 128)
    (&P_lds[0][0])[i] = __float2bfloat16(0.0f);

  bf16x8 qf0, qf1;
  {
    f32x4 qa0 = {0.f,0.f,0.f,0.f}, qa1 = qa0;
    const float* xq = query + (size_t)(b*SM + m0 + col16) * SH + kq;
    const float* w0 = Wq + (size_t)(h*HD + w*32 + col16) * SH + kq;
    const float* w1 = w0 + (size_t)16 * SH;
#pragma unroll
    for (int k0 = 0; k0 < SH; k0 += 32) {
      bf16x8 xa = ld8any(xq + k0);
      qa0 = mfma16(xa, ld8any(w0 + k0), qa0);
      qa1 = mfma16(xa, ld8any(w1 + k0), qa1);
    }
#pragma unroll
    for (int r = 0; r < 4; ++r) {
      q_lds[(wr + r)*QSTR + w*32 + col16]      = __float2bfloat16(qa0[r]);
      q_lds[(wr + r)*QSTR + w*32 + 16 + col16] = __float2bfloat16(qa1[r]);
    }
    __syncthreads();
    qf0 = ld8any(&q_lds[col16*QSTR + kq]);
    qf1 = ld8any(&q_lds[col16*QSTR + kq + 32]);
  }

  const bf16* kb = Kh + (size_t)(hb * SN) * HD + kq;
  const bf16* vb = VT + (size_t)(hb * HD) * SN;

  const int srow = tid >> 3, sj = tid & 7;
  float Mrun = -1.0e30f, Srun = 0.0f;
  const float span = spanv[h];
  const int dt0 = w * 16, dt1 = (w + 2) * 16;
  f32x4 o0 = {0.f,0.f,0.f,0.f}, o1 = o0;

  for (int ch = 0; ch < 16; ++ch) {
    const int l0 = ch << 6;
    const int nb_ = m0 + l0;

    f32x4 ca0 = {0.f,0.f,0.f,0.f}, ca1 = ca0, ca2 = ca0, pa0 = ca0, pa1 = ca0;
    {
      const bf16* kr0 = kb + (size_t)(nb_ + w*16 + col16) * HD;
      ca0 = mfma16(qf0, ld8any(kr0),           ca0);
      ca0 = mfma16(qf1, ld8any(kr0 + 32),      ca0);
      const bf16* kr1 = kr0 + 32 * HD;
      ca1 = mfma16(qf0, ld8any(kr1),           ca1);
      ca1 = mfma16(qf1, ld8any(kr1 + 32),      ca1);
      if (w == 0) {
        const bf16* kr2 = kr0 + 64 * HD;
        ca2 = mfma16(qf0, ld8any(kr2),         ca2);
        ca2 = mfma16(qf1, ld8any(kr2 + 32),    ca2);
      }
      const bf16* pr0 = peT + (size_t)(l0 + w*16 + col16) * HD + kq;
      pa0 = mfma16(qf0, ld8any(pr0),           pa0);
      pa0 = mfma16(qf1, ld8any(pr0 + 32),      pa0);
      const bf16* pr1 = pr0 + 32 * HD;
      pa1 = mfma16(qf0, ld8any(pr1),           pa1);
      pa1 = mfma16(qf1, ld8any(pr1 + 32),      pa1);
    }
#pragma unroll
    for (int r = 0; r < 4; ++r) {
      cont_lds[wr + r][w*16 + col16]      = ca0[r];
      cont_lds[wr + r][w*16 + 32 + col16] = ca1[r];
      if (w == 0) cont_lds[wr + r][64 + col16] = ca2[r];
      pos_lds[wr + r][w*16 + col16]       = pa0[r];
      pos_lds[wr + r][w*16 + 32 + col16]  = pa1[r];
    }
    __syncthreads();

    float sc[8];
    float mc = -1.0e30f;
    const float* crow = &cont_lds[srow][srow + sj*8];
    const float* prow = &pos_lds[srow][sj*8];
#pragma unroll
    for (int i = 0; i < 8; ++i) {
      float v = (crow[i] + prow[i]) * 0.125f;
      sc[i] = v;
      mc = fmaxf(mc, v);
    }
    mc = fmaxf(mc, __shfl_xor(mc, 1));
    mc = fmaxf(mc, __shfl_xor(mc, 2));
    mc = fmaxf(mc, __shfl_xor(mc, 4));
    const float Mnew = fmaxf(Mrun, mc);
    const float alpha = __expf(Mrun - Mnew);
    float ls = 0.0f;
    bf16* pwrow = &P_lds[srow][srow + sj*8];
#pragma unroll
    for (int i = 0; i < 8; ++i) {
      float p = __expf(sc[i] - Mnew);
      ls += p;
      const float tpl = (float)(l0 + sj*8 + i) - 1023.0f;
      float mv = (tpl + span * 1024.0f) * 0.03125f + 1.0f;
      mv = fminf(fmaxf(mv, 0.0f), 1.0f);
      pwrow[i] = __float2bfloat16(p * mv);
    }
    ls += __shfl_xor(ls, 1);
    ls += __shfl_xor(ls, 2);
    ls += __shfl_xor(ls, 4);
    Srun = Srun * alpha + ls;
    Mrun = Mnew;
    if (sj == 0) { alpha_lds[srow] = alpha; S_lds[srow] = Srun; }
    __syncthreads();

    float al[4];
#pragma unroll
    for (int r = 0; r < 4; ++r) al[r] = alpha_lds[wr + r];
#pragma unroll
    for (int r = 0; r < 4; ++r) { o0[r] *= al[r]; o1[r] *= al[r]; }
#pragma unroll
    for (int ks = 0; ks < 3; ++ks) {
      const bf16x8 ap = ld8any(&P_lds[col16][ks*32 + kq]);
      const bf16* v0 = vb + (size_t)(dt0 + col16) * SN + nb_ + ks*32 + kq;
      const bf16* v1 = vb + (size_t)(dt1 + col16) * SN + nb_ + ks*32 + kq;
      o0 = mfma16(ap, ld8any(v0), o0);
      o1 = mfma16(ap, ld8any(v1), o1);
    }
  }

  bf16* cr = ctx + (size_t)(b*SM + m0 + wr) * SH + h*HD + col16;
#pragma unroll
  for (int r = 0; r < 4; ++r) {
    const float inv = 1.0f / S_lds[wr + r];
    cr[(size_t)r * SH + dt0] = __float2bfloat16(o0[r] * inv);
    cr[(size_t)r * SH + dt1] = __float2bfloat16(o1[r] * inv);
  }
}

// ---------------------------------------------------------------------------
extern "C" void kernel_launch(void* const* d_in, const int* in_sizes, int n_in,
                              void* d_out, int out_size, void* d_ws, size_t ws_size,
                              hipStream_t stream) {
  const float* query  = (const float*)d_in[0];
  const float* key    = (const float*)d_in[1];
  const float* value  = (const float*)d_in[2];
  const float* key_pe = (const float*)d_in[3];
  const float* Wq     = (const float*)d_in[4];
  const float* Wk     = (const float*)d_in[5];
  const float* Wv     = (const float*)d_in[6];
  const float* Wo     = (const float*)d_in[7];
  const float* spanv  = (const float*)d_in[8];
  float* out = (float*)d_out;

  bf16* ws = (bf16*)d_ws;
  if (ws_size >= (size_t)48365568) {
    // Path C: fused-conversion fragment-linear pipeline, 4 launches.
    bf16* B0   = ws;                      // vF
    bf16* B1   = B0  + 6291456;           // (unused; layout kept)
    bf16* B2   = B1  + 6291456;           // kF
    bf16* qp   = B2  + 6291456;           // qpF
    bf16* ctxC = qp  + 2097152;           // attn ctx (fragment-linear)
    bf16* peF  = ctxC + 2097152;
    bf16* Wb   = peF + 65536;
    bf16* Wq_b = Wb, *Wk_b = Wb + 262144, *Wv_b = Wb + 524288, *Wo_b = Wb + 786432;

    // L1: weights + pe.
    prep_small<<<384, 256, 0, stream>>>(Wq, Wk, Wv, Wo, key_pe, Wb, peF);
    // L2: K+Q+V projections, XCD-aware block remap (panel-sharing blocks
    // co-located per XCD-L2).
    gemmKQV<<<896, 256, 0, stream>>>(key, query, value, Wk_b, Wq_b, Wv_b,
                                     B2, qp, B0);
    // L3: fused attention.
    attn1w<<<2048, 64, 0, stream>>>(qp, B2, B0, peF, spanv, ctxC);
    // L4: output projection.
    gemmO<<<256, 256, 0, stream>>>(ctxC, Wo_b, out);
  } else {
    // Path B (fallback): fused-q attention, f32 GEMM reads, 29.5 MB ws.
    bf16* k_head = ws;
    bf16* vT     = k_head + 6291456;
    bf16* ctx    = vT     + 6291456;
    bf16* peT    = ctx    + 2097152;
    gemmbn64<1, float, float, bf16><<<768, 256, 0, stream>>>(key,   Wk, k_head);
    gemmbn64<2, float, float, bf16><<<768, 256, 0, stream>>>(value, Wv, vT);
    transpose_pe_fb<<<256, 256, 0, stream>>>(key_pe, peT);
    attn_kernel_fb<<<2048, 128, 0, stream>>>(query, Wq, k_head, vT,
                                             peT, spanv, ctx);
    gemmbn64<0, bf16, float, float><<<256, 256, 0, stream>>>(ctx, Wo, out);
  }
}

// Round 13
// 182.778 us; speedup vs baseline: 1.0490x; 1.0281x over previous
//
#include <hip/hip_runtime.h>
#include <hip/hip_bf16.h>
#include <type_traits>

typedef __hip_bfloat16 bf16;
typedef short bf16x8 __attribute__((ext_vector_type(8)));
typedef float f32x4 __attribute__((ext_vector_type(4)));
typedef short short4_ __attribute__((ext_vector_type(4)));

#define NB 8      // batch
#define SM 512    // block size M
#define SL 1024   // attn span L
#define SH 512    // hidden
#define NH 8      // heads
#define HD 64     // head dim
#define SN 1536   // M + L (key length)

static __device__ __forceinline__ short bf_bits(float x) {
  union { bf16 b; short s; } u; u.b = __float2bfloat16(x); return u.s;
}
static __device__ __forceinline__ bf16x8 ld8any(const bf16* p) {
  return *reinterpret_cast<const bf16x8*>(p);
}
static __device__ __forceinline__ bf16x8 ld8any(const float* p) {
  float4 a = *reinterpret_cast<const float4*>(p);
  float4 b = *reinterpret_cast<const float4*>(p + 4);
  bf16x8 r;
  r[0] = bf_bits(a.x); r[1] = bf_bits(a.y); r[2] = bf_bits(a.z); r[3] = bf_bits(a.w);
  r[4] = bf_bits(b.x); r[5] = bf_bits(b.y); r[6] = bf_bits(b.z); r[7] = bf_bits(b.w);
  return r;
}
static __device__ __forceinline__ void st1(bf16* p, float v) { *p = __float2bfloat16(v); }
static __device__ __forceinline__ void st1(float* p, float v) { *p = v; }
static __device__ __forceinline__ f32x4 mfma16(bf16x8 a, bf16x8 b, f32x4 c) {
  return __builtin_amdgcn_mfma_f32_16x16x32_bf16(a, b, c, 0, 0, 0);
}

// ---------------------------------------------------------------------------
// Universal fragment-linear layout for an [R x C] matrix (C = 512):
//   FRAGIDX(row,col) = (row>>4)*8192 + (col>>5)*512
//                    + ((col>>3)&3)*128 + (row&15)*8 + (col&7)
// One wave MFMA fragment (16 rows x 32 cols) = 1KB contiguous, lane*16B.
// ---------------------------------------------------------------------------

// ---------------------------------------------------------------------------
// prep_all: all input conversions, ONE launch, LDS-staged so BOTH the
// f32 row-major reads AND the fragment-linear bf16 writes are coalesced.
//  [0,768)      key   -> kS      [768,1536)  value -> vS
//  [1536,1792)  query -> qS      [1792,1920) W -> Wb
//  [1920,2176)  pe -> peF  (256 blocks = FULL 65536 el; <=r10 had 32 = bug)
// ---------------------------------------------------------------------------
__global__ __launch_bounds__(256) void prep_all(
    const float* __restrict__ key, const float* __restrict__ value,
    const float* __restrict__ query,
    const float* __restrict__ Wq, const float* __restrict__ Wk,
    const float* __restrict__ Wv, const float* __restrict__ Wo,
    const float* __restrict__ pe,
    bf16* __restrict__ kS, bf16* __restrict__ vS, bf16* __restrict__ qS,
    bf16* __restrict__ Wb, bf16* __restrict__ peF) {
  __shared__ __align__(16) bf16 t[16 * 520];
  const int id = blockIdx.x, tid = threadIdx.x;
  if (id < 1920) {
    const float* src; bf16* dst;
    if (id < 768)       { src = key   + (size_t)id * 8192;
                          dst = kS    + (size_t)id * 8192; }
    else if (id < 1536) { src = value + (size_t)(id - 768) * 8192;
                          dst = vS    + (size_t)(id - 768) * 8192; }
    else if (id < 1792) { src = query + (size_t)(id - 1536) * 8192;
                          dst = qS    + (size_t)(id - 1536) * 8192; }
    else {
      const int s = id - 1792;
      const float* ws_[4] = {Wq, Wk, Wv, Wo};
      src = ws_[s >> 5] + (size_t)(s & 31) * 8192;
      dst = Wb + (size_t)(s >> 5) * 262144 + (size_t)(s & 31) * 8192;
    }
#pragma unroll
    for (int j = 0; j < 4; ++j) {
      const int i = j * 2048 + tid * 8;
      const bf16x8 v = ld8any(src + i);
      *reinterpret_cast<bf16x8*>(&t[(i >> 9) * 520 + (i & 511)]) = v;
    }
    __syncthreads();
#pragma unroll
    for (int j = 0; j < 4; ++j) {
      const int a = j * 2048 + tid * 8;
      const int kt5 = a >> 9, rest = a & 511;
      const int q = rest >> 7, rowl = (rest >> 3) & 15;
      *reinterpret_cast<bf16x8*>(dst + a) =
          *reinterpret_cast<const bf16x8*>(&t[rowl * 520 + kt5 * 32 + q * 8]);
    }
  } else {
    const int idx = (id - 1920) * 256 + tid;   // 0..65535, full peF
    const int l = idx >> 6, d = idx & 63;
    peF[(size_t)((l >> 4) * 2 + (d >> 5)) * 512
        + (size_t)((((d >> 3) & 3) * 16 + (l & 15)) * 8 + (d & 7))]
      = __float2bfloat16(pe[d * SL + l]);
  }
}

// ---------------------------------------------------------------------------
// gemm_dev2: Y[R x 512] = X @ W^T, X/W fragment-linear, BM=128 x BN=128,
// 4 waves, wave tile 64x64. v13: THREE-deep register pipeline (operands for
// kt+1 AND kt+2 in flight) -> ~2x the MFMA cover per load batch, matching
// L2-hit latency (round-12 lesson: these GEMMs are latency-bound, not
// BW-bound). sched_barrier pins each issue point.
// MODE 0: row-major TY. MODE 1: kF. MODE 2: vF (LDS transpose). MODE 3: qpF.
// ---------------------------------------------------------------------------
#define T2STR 136

#define GL2(AF, BF, KT)                                                      \
  {                                                                          \
    AF[0] = ld8any(xr +         (size_t)(KT) * 512);                         \
    AF[1] = ld8any(xr + 8192  + (size_t)(KT) * 512);                         \
    AF[2] = ld8any(xr + 16384 + (size_t)(KT) * 512);                         \
    AF[3] = ld8any(xr + 24576 + (size_t)(KT) * 512);                         \
    BF[0] = ld8any(wr +         (size_t)(KT) * 512);                         \
    BF[1] = ld8any(wr + 8192  + (size_t)(KT) * 512);                         \
    BF[2] = ld8any(wr + 16384 + (size_t)(KT) * 512);                         \
    BF[3] = ld8any(wr + 24576 + (size_t)(KT) * 512);                         \
  }

#define MF44(AF, BF)                                                         \
  {                                                                          \
    _Pragma("unroll")                                                        \
    for (int mt = 0; mt < 4; ++mt)                                           \
      _Pragma("unroll")                                                      \
      for (int nt = 0; nt < 4; ++nt)                                         \
        acc[mt][nt] = mfma16(AF[mt], BF[nt], acc[mt][nt]);                   \
  }

template <int MODE, typename TY>
static __device__ __forceinline__ void gemm_dev2(const bf16* __restrict__ XF,
                                                 const bf16* __restrict__ WF,
                                                 TY* __restrict__ Y,
                                                 int xblk, int yblk, bf16* tile) {
  const int tid  = threadIdx.x;
  const int lane = tid & 63, w = tid >> 6;
  const int col16 = lane & 15, quad = lane >> 4;
  const int lane8 = lane * 8;
  const int wm = w >> 1, wn = w & 1;
  const int m0 = xblk * 128 + wm * 64;
  const int n0 = yblk * 128 + wn * 64;
  const bf16* xr = XF + (size_t)(m0 >> 4) * 8192 + lane8;
  const bf16* wr = WF + (size_t)(n0 >> 4) * 8192 + lane8;
  f32x4 acc[4][4];
#pragma unroll
  for (int i = 0; i < 4; ++i)
#pragma unroll
    for (int j = 0; j < 4; ++j) acc[i][j] = f32x4{0.f,0.f,0.f,0.f};

  bf16x8 afA[4], bfA[4], afB[4], bfB[4], afC[4], bfC[4];
  GL2(afA, bfA, 0);
  GL2(afB, bfB, 1);
  __builtin_amdgcn_sched_barrier(0);
#pragma unroll
  for (int kt = 0; kt < 16; ++kt) {
    const int nxt = kt + 2;
    if (nxt < 16) {
      if (nxt % 3 == 0)      { GL2(afA, bfA, nxt); }
      else if (nxt % 3 == 1) { GL2(afB, bfB, nxt); }
      else                   { GL2(afC, bfC, nxt); }
      __builtin_amdgcn_sched_barrier(0);
    }
    if (kt % 3 == 0)      MF44(afA, bfA)
    else if (kt % 3 == 1) MF44(afB, bfB)
    else                  MF44(afC, bfC)
  }

  if constexpr (MODE == 0) {
#pragma unroll
    for (int mt = 0; mt < 4; ++mt)
#pragma unroll
      for (int r = 0; r < 4; ++r) {
        const int row = m0 + mt*16 + quad*4 + r;
        TY* yr = Y + (size_t)row * SH + n0 + col16;
#pragma unroll
        for (int nt = 0; nt < 4; ++nt) st1(yr + nt*16, acc[mt][nt][r]);
      }
  } else if constexpr (MODE == 1) {
    // kF: head h = n0>>6; within-half idx = key8 + q*128 + de.
    const int dq = col16 >> 3, de = col16 & 7;
    const int head = n0 >> 6;
#pragma unroll
    for (int mt = 0; mt < 4; ++mt)
#pragma unroll
      for (int r = 0; r < 4; ++r) {
        const int row = m0 + mt*16 + quad*4 + r;
        const int b = row / SN, sr = row - b * SN;
        bf16* yr = (bf16*)Y
            + (((size_t)(b*NH + head)*96 + (sr>>4))*2)*512
            + (size_t)((sr&15)*8 + de);
#pragma unroll
        for (int nt = 0; nt < 4; ++nt)
          yr[(nt>>1)*512 + ((nt&1)*2 + dq)*128] = __float2bfloat16(acc[mt][nt][r]);
      }
  } else if constexpr (MODE == 3) {
    const int dq = col16 >> 3, de = col16 & 7;
    const int c5b = n0 >> 5;
#pragma unroll
    for (int mt = 0; mt < 4; ++mt)
#pragma unroll
      for (int r = 0; r < 4; ++r) {
        bf16* yr = (bf16*)Y + (size_t)((m0>>4) + mt) * 8192
                 + (size_t)((quad*4 + r)*8 + de);
#pragma unroll
        for (int nt = 0; nt < 4; ++nt)
          yr[(c5b + (nt>>1))*512 + ((nt&1)*2 + dq)*128] = __float2bfloat16(acc[mt][nt][r]);
      }
  } else {
    // vF via LDS transpose: tile[d 0..127][row_loc 0..127]
#pragma unroll
    for (int mt = 0; mt < 4; ++mt)
#pragma unroll
      for (int r = 0; r < 4; ++r) {
        const int row_loc = wm*64 + mt*16 + quad*4 + r;
#pragma unroll
        for (int nt = 0; nt < 4; ++nt) {
          const int d = wn*64 + nt*16 + col16;
          tile[d * T2STR + row_loc] = __float2bfloat16(acc[mt][nt][r]);
        }
      }
    __syncthreads();
    const int d  = tid >> 1;      // 0..127
    const int hq = tid & 1;       // 64-row half
    const bf16* src = tile + d * T2STR + hq * 64;
    const int row0 = xblk*128 + hq*64;
    const int b = row0 / SN, sr0 = row0 - b * SN;
    const int head = yblk*2 + (d >> 6);
    const int dd = d & 63;
    bf16* dstF = (bf16*)Y + (((size_t)(b*NH + head)*4 + (dd>>4))*96)*256
               + (size_t)(dd&15)*8;
#pragma unroll
    for (int i = 0; i < 8; ++i) {
      const int key = sr0 + i*8;
      const size_t off = (size_t)(key>>4)*256 + (size_t)((key>>3)&1)*128;
      *reinterpret_cast<uint4*>(dstF + off) = reinterpret_cast<const uint4*>(src)[i];
    }
  }
}

// XCD-aware remap (round-12 proven: FETCH 116->35 MB): within each 32-block
// supergroup, xblk = g*8 + (lid&7), yblk = (lid>>3)&3 -> the 4 blocks
// sharing an X panel are spaced 8 apart in id = same XCD = panel fetched
// once per XCD-L2 and re-reads are L2 HITS (latency win for the
// latency-bound register-DB structure).
static __device__ __forceinline__ void xcd_remap(int lid, int& xblk, int& yblk) {
  xblk = (lid >> 5) * 8 + (lid & 7);
  yblk = (lid >> 3) & 3;
}

// Merged K+Q projection: [0,384) K-proj (mode 1), [384,512) Q-proj (mode 3).
__global__ __launch_bounds__(256, 2) void gemmKQ(
    const bf16* __restrict__ XK, const bf16* __restrict__ WK, bf16* __restrict__ YK,
    const bf16* __restrict__ XQ, const bf16* __restrict__ WQ, bf16* __restrict__ YQ) {
  __shared__ bf16 dummy[8];
  const int id = blockIdx.x;
  int xblk, yblk;
  if (id < 384) {
    xcd_remap(id, xblk, yblk);
    gemm_dev2<1, bf16>(XK, WK, YK, xblk, yblk, dummy);
  } else {
    xcd_remap(id - 384, xblk, yblk);   // 384 = 12*32 -> id mod 8 preserved
    gemm_dev2<3, bf16>(XQ, WQ, YQ, xblk, yblk, dummy);
  }
}

__global__ __launch_bounds__(256, 2) void gemmV(
    const bf16* __restrict__ XF, const bf16* __restrict__ WF, bf16* __restrict__ Y) {
  __shared__ __align__(16) bf16 tile[128 * T2STR];
  int xblk, yblk;
  xcd_remap(blockIdx.x, xblk, yblk);
  gemm_dev2<2, bf16>(XF, WF, Y, xblk, yblk, tile);
}

// ---------------------------------------------------------------------------
// gemmO: 64x32 wave tile (BM=128, BN=64), grid 256 -> full-GPU coverage.
// v13: 3-deep register pipeline. Existing id mapping already co-locates the
// 8 panel-sharing blocks on one XCD (spaced 8 apart).
// ---------------------------------------------------------------------------
#define GLO(AF, BF, KT)                                                      \
  {                                                                          \
    AF[0] = ld8any(xr +         (size_t)(KT) * 512);                         \
    AF[1] = ld8any(xr + 8192  + (size_t)(KT) * 512);                         \
    AF[2] = ld8any(xr + 16384 + (size_t)(KT) * 512);                         \
    AF[3] = ld8any(xr + 24576 + (size_t)(KT) * 512);                         \
    BF[0] = ld8any(wr +         (size_t)(KT) * 512);                         \
    BF[1] = ld8any(wr + 8192  + (size_t)(KT) * 512);                         \
  }

#define MF42(AF, BF)                                                         \
  {                                                                          \
    _Pragma("unroll")                                                        \
    for (int mt = 0; mt < 4; ++mt)                                           \
      _Pragma("unroll")                                                      \
      for (int nt = 0; nt < 2; ++nt)                                         \
        acc[mt][nt] = mfma16(AF[mt], BF[nt], acc[mt][nt]);                   \
  }

__global__ __launch_bounds__(256, 2) void gemmO(
    const bf16* __restrict__ XF, const bf16* __restrict__ WF, float* __restrict__ Y) {
  const int id   = blockIdx.x;
  const int s_   = id >> 3;
  const int xblk = (id & 7) + 8 * (s_ >> 3);
  const int yblk = s_ & 7;
  const int tid  = threadIdx.x;
  const int lane = tid & 63, w = tid >> 6;
  const int col16 = lane & 15, quad = lane >> 4;
  const int lane8 = lane * 8;
  const int wm = w >> 1, wn = w & 1;
  const int m0 = xblk * 128 + wm * 64;
  const int n0 = yblk * 64 + wn * 32;
  const bf16* xr = XF + (size_t)(m0 >> 4) * 8192 + lane8;
  const bf16* wr = WF + (size_t)(n0 >> 4) * 8192 + lane8;
  f32x4 acc[4][2];
#pragma unroll
  for (int i = 0; i < 4; ++i)
#pragma unroll
    for (int j = 0; j < 2; ++j) acc[i][j] = f32x4{0.f,0.f,0.f,0.f};

  bf16x8 afA[4], bfA[2], afB[4], bfB[2], afC[4], bfC[2];
  GLO(afA, bfA, 0);
  GLO(afB, bfB, 1);
  __builtin_amdgcn_sched_barrier(0);
#pragma unroll
  for (int kt = 0; kt < 16; ++kt) {
    const int nxt = kt + 2;
    if (nxt < 16) {
      if (nxt % 3 == 0)      { GLO(afA, bfA, nxt); }
      else if (nxt % 3 == 1) { GLO(afB, bfB, nxt); }
      else                   { GLO(afC, bfC, nxt); }
      __builtin_amdgcn_sched_barrier(0);
    }
    if (kt % 3 == 0)      MF42(afA, bfA)
    else if (kt % 3 == 1) MF42(afB, bfB)
    else                  MF42(afC, bfC)
  }
#pragma unroll
  for (int mt = 0; mt < 4; ++mt)
#pragma unroll
    for (int r = 0; r < 4; ++r) {
      const int row = m0 + mt*16 + quad*4 + r;
      float* yr = Y + (size_t)row * SH + n0 + col16;
      yr[0]  = acc[mt][0][r];
      yr[16] = acc[mt][1][r];
    }
}

// ---------------------------------------------------------------------------
// Barrier-free wave-private fused attention (round-10 proven, ~45 us).
// ---------------------------------------------------------------------------
#define PSTR1 69    // pos stride (f32): scalar writes, b128-aligned reads
#define BSTR1 104   // P stride (bf16): b64 writes, b128 reads aligned

__global__ __launch_bounds__(64, 2) void attn1w(
    const bf16* __restrict__ qp, const bf16* __restrict__ Kh,
    const bf16* __restrict__ VT, const bf16* __restrict__ peT,
    const float* __restrict__ spanv, bf16* __restrict__ ctx) {
  __shared__ __align__(16) float pos_s[16 * PSTR1];
  __shared__ __align__(16) bf16  P_s[16 * BSTR1];

  const int id = blockIdx.x;
  const int h  = id & 7;
  const int s_ = id >> 3;
  const int m0 = (s_ & 31) * 16;
  const int b  = s_ >> 5;
  const int hb = b * 8 + h;
  const int lane  = threadIdx.x;
  const int col16 = lane & 15, quad = lane >> 4, kq = quad << 3;
  const int q4 = quad << 2;
  const int lane8 = lane * 8;

  // zero P band once (cols 80..103 stay zero; read by ks=2 PV fragment)
  for (int i = lane; i < 16 * BSTR1; i += 64)
    P_s[i] = __float2bfloat16(0.0f);

  // q from fragment-linear qp: rt*8192 + h*1024 + lane*8 (and +512)
  const bf16* qb = qp + (size_t)((b*SM + m0) >> 4) * 8192 + h*1024 + lane8;
  const bf16x8 qf0 = ld8any(qb), qf1 = ld8any(qb + 512);

  const bf16* kbF = Kh + (size_t)hb * 98304 + lane8;   // 96 tiles * 1024
  const bf16* vbF = VT + (size_t)hb * 98304 + lane8;   // 4 dt * 96 kt * 256
  const bf16* pbF = peT + lane8;

  float Mrun = -1.0e30f, Srun = 0.0f;
  const float span1024 = spanv[h] * 1024.0f;
  f32x4 o[4];
#pragma unroll
  for (int dt = 0; dt < 4; ++dt) o[dt] = f32x4{0.f,0.f,0.f,0.f};

  // loop-invariant per-lane softmax constants
  float bias_[5][4], mvs_[5][4];
  {
    const float mvb = ((float)(q4 - col16 - 1023) + span1024) * 0.03125f + 1.0f;
#pragma unroll
    for (int t = 0; t < 5; ++t)
#pragma unroll
      for (int r = 0; r < 4; ++r) {
        const int l = 16*t + q4 + r - col16;
        bias_[t][r] = ((unsigned)l < 64u) ? 0.0f : -1.0e30f;
        mvs_[t][r]  = mvb + (float)(16*t + r) * 0.03125f;
      }
  }

  // prefetched operand fragments (single-buffered; WAR ordering via reg deps)
  bf16x8 kf[5][2], pf[4][2], vf[4][3];

  // ---- prologue: chunk-0 operands ----
  {
    const int tk0 = m0 >> 4;
#pragma unroll
    for (int t = 0; t < 5; ++t) {
      const bf16* kr = kbF + (size_t)(tk0 + t) * 1024;
      kf[t][0] = ld8any(kr); kf[t][1] = ld8any(kr + 512);
    }
#pragma unroll
    for (int t = 0; t < 4; ++t) {
      const bf16* pr = pbF + (size_t)t * 1024;
      pf[t][0] = ld8any(pr); pf[t][1] = ld8any(pr + 512);
    }
#pragma unroll
    for (int dt = 0; dt < 4; ++dt) {
      const bf16* v0 = vbF + (size_t)dt * 24576 + (size_t)tk0 * 256;
#pragma unroll
      for (int ks = 0; ks < 3; ++ks) vf[dt][ks] = ld8any(v0 + ks*512);
    }
    __builtin_amdgcn_sched_barrier(0);
  }

  const int posw = col16 * PSTR1 + q4;        // write base (scalar f32)
  const int posr = col16 * (PSTR1 - 1) + q4;  // read base (b128-aligned)
  const int pww  = col16 * BSTR1 + q4;        // P write base (b64-aligned)
  const int pwr  = col16 * BSTR1 + kq;        // P read base (b128-aligned)

  for (int ch = 0; ch < 16; ++ch) {
    const int l0 = ch << 6;

    // ---- pos MFMAs (swapped: A=pe rows, D rows = l, cols = q-row) ----
    f32x4 pacc[4];
#pragma unroll
    for (int t = 0; t < 4; ++t) {
      f32x4 a = {0.f,0.f,0.f,0.f};
      a = mfma16(pf[t][0], qf0, a);
      a = mfma16(pf[t][1], qf1, a);
      pacc[t] = a;
    }
#pragma unroll
    for (int t = 0; t < 4; ++t)
#pragma unroll
      for (int r = 0; r < 4; ++r)
        pos_s[posw + 16*t + r] = pacc[t][r];

    // ---- cont MFMAs (swapped: A=K rows, D rows = band pos, cols = q-row) ----
    f32x4 cacc[5];
#pragma unroll
    for (int t = 0; t < 5; ++t) {
      f32x4 a = {0.f,0.f,0.f,0.f};
      a = mfma16(kf[t][0], qf0, a);
      a = mfma16(kf[t][1], qf1, a);
      cacc[t] = a;
    }

    // ---- issue next chunk's K/pe (kf/pf regs now dead); pinned ----
    {
      const int l0n = (ch < 15) ? l0 + 64 : l0;
      const int tkn = (m0 + l0n) >> 4;
      const int tpn = l0n >> 4;
#pragma unroll
      for (int t = 0; t < 5; ++t) {
        const bf16* kr = kbF + (size_t)(tkn + t) * 1024;
        kf[t][0] = ld8any(kr); kf[t][1] = ld8any(kr + 512);
      }
#pragma unroll
      for (int t = 0; t < 4; ++t) {
        const bf16* pr = pbF + (size_t)(tpn + t) * 1024;
        pf[t][0] = ld8any(pr); pf[t][1] = ld8any(pr + 512);
      }
      __builtin_amdgcn_sched_barrier(0);
    }

    // ---- per-lane softmax over this row's 64-key window ----
    float sc[5][4];
    float mc = -1.0e30f;
#pragma unroll
    for (int t = 0; t < 5; ++t) {
      const f32x4 pv4 = *reinterpret_cast<const f32x4*>(&pos_s[posr + 16*t]);
#pragma unroll
      for (int r = 0; r < 4; ++r) {
        const float v = fmaf(cacc[t][r] + pv4[r], 0.125f, bias_[t][r]);
        sc[t][r] = v;
        mc = fmaxf(mc, v);
      }
    }
    mc = fmaxf(mc, __shfl_xor(mc, 16));
    mc = fmaxf(mc, __shfl_xor(mc, 32));
    const float Mnew = fmaxf(Mrun, mc);
    const bool defer = __all(Mnew - Mrun <= 8.0f);
    const float Mb = defer ? Mrun : Mnew;      // wave-uniform select
    const float chf = (float)ch * 2.0f;        // l0 * 0.03125
    float ls = 0.0f;
#pragma unroll
    for (int t = 0; t < 5; ++t) {
      short4_ pk;
#pragma unroll
      for (int r = 0; r < 4; ++r) {
        const float p = __expf(sc[t][r] - Mb);  // 0 for masked slots
        ls += p;
        float mv = mvs_[t][r] + chf;
        mv = fminf(fmaxf(mv, 0.0f), 1.0f);
        pk[r] = bf_bits(p * mv);
      }
      *reinterpret_cast<short4_*>(&P_s[pww + 16*t]) = pk;
    }
    ls += __shfl_xor(ls, 16);
    ls += __shfl_xor(ls, 32);

    if (defer) {
      Srun += ls;                 // no rescale, Mrun unchanged
    } else {
      const float alpha = __expf(Mrun - Mnew);
      Srun = Srun * alpha + ls;
      Mrun = Mnew;
#pragma unroll
      for (int dt = 0; dt < 4; ++dt)
#pragma unroll
        for (int r = 0; r < 4; ++r) o[dt][r] *= alpha;
    }

    // ---- PV (swapped: A=V^T rows=d, B=P cols=q-row) ----
#pragma unroll
    for (int ks = 0; ks < 3; ++ks) {
      const bf16x8 ap = ld8any(&P_s[pwr + ks*32]);
#pragma unroll
      for (int dt = 0; dt < 4; ++dt)
        o[dt] = mfma16(vf[dt][ks], ap, o[dt]);
    }

    // ---- issue next chunk's V (vf regs now dead); pinned ----
    {
      const int tkn = (m0 + ((ch < 15) ? l0 + 64 : l0)) >> 4;
#pragma unroll
      for (int dt = 0; dt < 4; ++dt) {
        const bf16* v0 = vbF + (size_t)dt * 24576 + (size_t)tkn * 256;
#pragma unroll
        for (int ks = 0; ks < 3; ++ks) vf[dt][ks] = ld8any(v0 + ks*512);
      }
      __builtin_amdgcn_sched_barrier(0);
    }
  }

  // ---- epilogue: lane-local normalize, fragment-linear ctx stores ----
  const float inv = 1.0f / Srun;
  bf16* crb = ctx + (size_t)((b*SM + m0) >> 4) * 8192
            + (size_t)(h*1024 + (quad>>1)*128 + col16*8 + (quad&1)*4);
#pragma unroll
  for (int dt = 0; dt < 4; ++dt) {
    short4_ pk;
#pragma unroll
    for (int r = 0; r < 4; ++r) pk[r] = bf_bits(o[dt][r] * inv);
    *reinterpret_cast<short4_*>(crb + (size_t)(dt>>1)*512 + (dt&1)*256) = pk;
  }
}

// ---------------------------------------------------------------------------
// Fallback path kernels (round-6 proven, old row-major layouts).
// ---------------------------------------------------------------------------
template <int MODE, typename TX, typename TW, typename TY>
__global__ __launch_bounds__(256) void gemmbn64(const TX* __restrict__ X,
                                                const TW* __restrict__ W,
                                                TY* __restrict__ Y) {
  __shared__ __align__(16) bf16 tile[(MODE == 2) ? 64 * T2STR : 8];
  const int id   = blockIdx.x;
  const int s_   = id >> 3;
  const int xblk = (id & 7) + 8 * (s_ >> 3);
  const int yblk = s_ & 7;
  const int tid  = threadIdx.x;
  const int lane = tid & 63, w = tid >> 6;
  const int col16 = lane & 15, quad = lane >> 4, kq = quad << 3;
  const int wm = w >> 1, wn = w & 1;
  const int m0 = xblk * 128 + wm * 64;
  const int n0 = yblk * 64 + wn * 32;
  const TX* xr = X + (size_t)(m0 + col16) * SH + kq;
  const TW* wr = W + (size_t)(n0 + col16) * SH + kq;
  f32x4 acc[4][2];
#pragma unroll
  for (int i = 0; i < 4; ++i)
#pragma unroll
    for (int j = 0; j < 2; ++j) acc[i][j] = f32x4{0.f,0.f,0.f,0.f};
#pragma unroll
  for (int k0 = 0; k0 < SH; k0 += 32) {
    bf16x8 af[4], bfr[2];
#pragma unroll
    for (int t = 0; t < 4; ++t) af[t]  = ld8any(xr + (size_t)(t*16) * SH + k0);
#pragma unroll
    for (int t = 0; t < 2; ++t) bfr[t] = ld8any(wr + (size_t)(t*16) * SH + k0);
#pragma unroll
    for (int mt = 0; mt < 4; ++mt)
#pragma unroll
      for (int nt = 0; nt < 2; ++nt)
        acc[mt][nt] = mfma16(af[mt], bfr[nt], acc[mt][nt]);
  }

  if constexpr (MODE == 0) {
#pragma unroll
    for (int mt = 0; mt < 4; ++mt)
#pragma unroll
      for (int r = 0; r < 4; ++r) {
        const int row = m0 + mt*16 + quad*4 + r;
        TY* yr = Y + (size_t)row * SH + n0 + col16;
        st1(yr,      acc[mt][0][r]);
        st1(yr + 16, acc[mt][1][r]);
      }
  } else if constexpr (MODE == 1) {
#pragma unroll
    for (int mt = 0; mt < 4; ++mt)
#pragma unroll
      for (int r = 0; r < 4; ++r) {
        const int row = m0 + mt*16 + quad*4 + r;
        const int b = row / SN, sr = row - b * SN;
        bf16* yr = (bf16*)Y + (size_t)((b*NH + yblk)*SN + sr) * HD
                 + wn*32 + col16;
        yr[0]  = __float2bfloat16(acc[mt][0][r]);
        yr[16] = __float2bfloat16(acc[mt][1][r]);
      }
  } else {
#pragma unroll
    for (int mt = 0; mt < 4; ++mt)
#pragma unroll
      for (int r = 0; r < 4; ++r) {
        const int row_loc = wm*64 + mt*16 + quad*4 + r;
#pragma unroll
        for (int nt = 0; nt < 2; ++nt) {
          const int d = wn*32 + nt*16 + col16;
          tile[d * T2STR + row_loc] = __float2bfloat16(acc[mt][nt][r]);
        }
      }
    __syncthreads();
    const int d  = tid >> 2;
    const int hq = tid & 3;
    const bf16* src = tile + d * T2STR + hq * 32;
    const int row0 = xblk*128 + hq*32;
    const int b = row0 / SN, sr0 = row0 - b * SN;
    bf16* dst = (bf16*)Y + (size_t)((b*NH + yblk)*HD + d) * SN + sr0;
#pragma unroll
    for (int i = 0; i < 4; ++i)
      reinterpret_cast<uint4*>(dst)[i] = reinterpret_cast<const uint4*>(src)[i];
  }
}

__global__ void transpose_pe_fb(const float* __restrict__ pe, bf16* __restrict__ peT) {
  int idx = blockIdx.x * 256 + threadIdx.x;
  int l = idx >> 6, d = idx & 63;
  peT[idx] = __float2bfloat16(pe[d * SL + l]);
}

#define MT 16
#define CSTR 84
#define PSTR 65
#define BSTR 104
#define QSTR 72

__global__ __launch_bounds__(128) void attn_kernel_fb(
    const float* __restrict__ query, const float* __restrict__ Wq,
    const bf16* __restrict__ Kh, const bf16* __restrict__ VT,
    const bf16* __restrict__ peT, const float* __restrict__ spanv,
    bf16* __restrict__ ctx) {
  __shared__ __align__(16) float cont_lds[MT][CSTR];
  __shared__ __align__(16) float pos_lds[MT][PSTR];
  __shared__ __align__(16) bf16  P_lds[MT][BSTR];
  __shared__ __align__(16) bf16  q_lds[MT*QSTR];
  __shared__ float alpha_lds[MT];
  __shared__ float S_lds[MT];

  const int id = blockIdx.x;
  const int h  = id & 7;
  const int s_ = id >> 3;
  const int m0 = (s_ & 31) * MT;
  const int b  = s_ >> 5;
  const int hb = b * 8 + h;
  const int tid  = threadIdx.x;
  const int lane = tid & 63;
  const int w    = tid >> 6;
  const int col16 = lane & 15, quad = lane >> 4, kq = quad << 3;
  const int wr = quad << 2;

  for (int i = tid; i < MT * BSTR; i += 128)
    (&P_lds[0][0])[i] = __float2bfloat16(0.0f);

  bf16x8 qf0, qf1;
  {
    f32x4 qa0 = {0.f,0.f,0.f,0.f}, qa1 = qa0;
    const float* xq = query + (size_t)(b*SM + m0 + col16) * SH + kq;
    const float* w0 = Wq + (size_t)(h*HD + w*32 + col16) * SH + kq;
    const float* w1 = w0 + (size_t)16 * SH;
#pragma unroll
    for (int k0 = 0; k0 < SH; k0 += 32) {
      bf16x8 xa = ld8any(xq + k0);
      qa0 = mfma16(xa, ld8any(w0 + k0), qa0);
      qa1 = mfma16(xa, ld8any(w1 + k0), qa1);
    }
#pragma unroll
    for (int r = 0; r < 4; ++r) {
      q_lds[(wr + r)*QSTR + w*32 + col16]      = __float2bfloat16(qa0[r]);
      q_lds[(wr + r)*QSTR + w*32 + 16 + col16] = __float2bfloat16(qa1[r]);
    }
    __syncthreads();
    qf0 = ld8any(&q_lds[col16*QSTR + kq]);
    qf1 = ld8any(&q_lds[col16*QSTR + kq + 32]);
  }

  const bf16* kb = Kh + (size_t)(hb * SN) * HD + kq;
  const bf16* vb = VT + (size_t)(hb * HD) * SN;

  const int srow = tid >> 3, sj = tid & 7;
  float Mrun = -1.0e30f, Srun = 0.0f;
  const float span = spanv[h];
  const int dt0 = w * 16, dt1 = (w + 2) * 16;
  f32x4 o0 = {0.f,0.f,0.f,0.f}, o1 = o0;

  for (int ch = 0; ch < 16; ++ch) {
    const int l0 = ch << 6;
    const int nb_ = m0 + l0;

    f32x4 ca0 = {0.f,0.f,0.f,0.f}, ca1 = ca0, ca2 = ca0, pa0 = ca0, pa1 = ca0;
    {
      const bf16* kr0 = kb + (size_t)(nb_ + w*16 + col16) * HD;
      ca0 = mfma16(qf0, ld8any(kr0),           ca0);
      ca0 = mfma16(qf1, ld8any(kr0 + 32),      ca0);
      const bf16* kr1 = kr0 + 32 * HD;
      ca1 = mfma16(qf0, ld8any(kr1),           ca1);
      ca1 = mfma16(qf1, ld8any(kr1 + 32),      ca1);
      if (w == 0) {
        const bf16* kr2 = kr0 + 64 * HD;
        ca2 = mfma16(qf0, ld8any(kr2),         ca2);
        ca2 = mfma16(qf1, ld8any(kr2 + 32),    ca2);
      }
      const bf16* pr0 = peT + (size_t)(l0 + w*16 + col16) * HD + kq;
      pa0 = mfma16(qf0, ld8any(pr0),           pa0);
      pa0 = mfma16(qf1, ld8any(pr0 + 32),      pa0);
      const bf16* pr1 = pr0 + 32 * HD;
      pa1 = mfma16(qf0, ld8any(pr1),           pa1);
      pa1 = mfma16(qf1, ld8any(pr1 + 32),      pa1);
    }
#pragma unroll
    for (int r = 0; r < 4; ++r) {
      cont_lds[wr + r][w*16 + col16]      = ca0[r];
      cont_lds[wr + r][w*16 + 32 + col16] = ca1[r];
      if (w == 0) cont_lds[wr + r][64 + col16] = ca2[r];
      pos_lds[wr + r][w*16 + col16]       = pa0[r];
      pos_lds[wr + r][w*16 + 32 + col16]  = pa1[r];
    }
    __syncthreads();

    float sc[8];
    float mc = -1.0e30f;
    const float* crow = &cont_lds[srow][srow + sj*8];
    const float* prow = &pos_lds[srow][sj*8];
#pragma unroll
    for (int i = 0; i < 8; ++i) {
      float v = (crow[i] + prow[i]) * 0.125f;
      sc[i] = v;
      mc = fmaxf(mc, v);
    }
    mc = fmaxf(mc, __shfl_xor(mc, 1));
    mc = fmaxf(mc, __shfl_xor(mc, 2));
    mc = fmaxf(mc, __shfl_xor(mc, 4));
    const float Mnew = fmaxf(Mrun, mc);
    const float alpha = __expf(Mrun - Mnew);
    float ls = 0.0f;
    bf16* pwrow = &P_lds[srow][srow + sj*8];
#pragma unroll
    for (int i = 0; i < 8; ++i) {
      float p = __expf(sc[i] - Mnew);
      ls += p;
      const float tpl = (float)(l0 + sj*8 + i) - 1023.0f;
      float mv = (tpl + span * 1024.0f) * 0.03125f + 1.0f;
      mv = fminf(fmaxf(mv, 0.0f), 1.0f);
      pwrow[i] = __float2bfloat16(p * mv);
    }
    ls += __shfl_xor(ls, 1);
    ls += __shfl_xor(ls, 2);
    ls += __shfl_xor(ls, 4);
    Srun = Srun * alpha + ls;
    Mrun = Mnew;
    if (sj == 0) { alpha_lds[srow] = alpha; S_lds[srow] = Srun; }
    __syncthreads();

    float al[4];
#pragma unroll
    for (int r = 0; r < 4; ++r) al[r] = alpha_lds[wr + r];
#pragma unroll
    for (int r = 0; r < 4; ++r) { o0[r] *= al[r]; o1[r] *= al[r]; }
#pragma unroll
    for (int ks = 0; ks < 3; ++ks) {
      const bf16x8 ap = ld8any(&P_lds[col16][ks*32 + kq]);
      const bf16* v0 = vb + (size_t)(dt0 + col16) * SN + nb_ + ks*32 + kq;
      const bf16* v1 = vb + (size_t)(dt1 + col16) * SN + nb_ + ks*32 + kq;
      o0 = mfma16(ap, ld8any(v0), o0);
      o1 = mfma16(ap, ld8any(v1), o1);
    }
  }

  bf16* cr = ctx + (size_t)(b*SM + m0 + wr) * SH + h*HD + col16;
#pragma unroll
  for (int r = 0; r < 4; ++r) {
    const float inv = 1.0f / S_lds[wr + r];
    cr[(size_t)r * SH + dt0] = __float2bfloat16(o0[r] * inv);
    cr[(size_t)r * SH + dt1] = __float2bfloat16(o1[r] * inv);
  }
}

// ---------------------------------------------------------------------------
extern "C" void kernel_launch(void* const* d_in, const int* in_sizes, int n_in,
                              void* d_out, int out_size, void* d_ws, size_t ws_size,
                              hipStream_t stream) {
  const float* query  = (const float*)d_in[0];
  const float* key    = (const float*)d_in[1];
  const float* value  = (const float*)d_in[2];
  const float* key_pe = (const float*)d_in[3];
  const float* Wq     = (const float*)d_in[4];
  const float* Wk     = (const float*)d_in[5];
  const float* Wv     = (const float*)d_in[6];
  const float* Wo     = (const float*)d_in[7];
  const float* spanv  = (const float*)d_in[8];
  float* out = (float*)d_out;

  bf16* ws = (bf16*)d_ws;
  if (ws_size >= (size_t)48365568) {
    // Path C: fragment-linear pipeline, 5 launches (round-10 topology +
    // 3-deep GEMM pipelines + XCD remap + pe fix).
    bf16* B0   = ws;                      // stgK -> vF
    bf16* B1   = B0  + 6291456;           // stgV
    bf16* B2   = B1  + 6291456;           // kF
    bf16* qp   = B2  + 6291456;           // qpF
    bf16* ctxC = qp  + 2097152;           // qF staging, then attn ctx
    bf16* peF  = ctxC + 2097152;
    bf16* Wb   = peF + 65536;
    bf16* Wq_b = Wb, *Wk_b = Wb + 262144, *Wv_b = Wb + 524288, *Wo_b = Wb + 786432;

    prep_all<<<2176, 256, 0, stream>>>(key, value, query, Wq, Wk, Wv, Wo,
                                       key_pe, B0, B1, ctxC, Wb, peF);
    gemmKQ<<<512, 256, 0, stream>>>(B0, Wk_b, B2, ctxC, Wq_b, qp);
    gemmV<<<384, 256, 0, stream>>>(B1, Wv_b, B0);
    attn1w<<<2048, 64, 0, stream>>>(qp, B2, B0, peF, spanv, ctxC);
    gemmO<<<256, 256, 0, stream>>>(ctxC, Wo_b, out);
  } else {
    // Path B (fallback): fused-q attention, f32 GEMM reads, 29.5 MB ws.
    bf16* k_head = ws;
    bf16* vT     = k_head + 6291456;
    bf16* ctx    = vT     + 6291456;
    bf16* peT    = ctx    + 2097152;
    gemmbn64<1, float, float, bf16><<<768, 256, 0, stream>>>(key,   Wk, k_head);
    gemmbn64<2, float, float, bf16><<<768, 256, 0, stream>>>(value, Wv, vT);
    transpose_pe_fb<<<256, 256, 0, stream>>>(key_pe, peT);
    attn_kernel_fb<<<2048, 128, 0, stream>>>(query, Wq, k_head, vT,
                                             peT, spanv, ctx);
    gemmbn64<0, bf16, float, float><<<256, 256, 0, stream>>>(ctx, Wo, out);
  }
}

// Round 14
// 172.406 us; speedup vs baseline: 1.1121x; 1.0602x over previous
//
#include <hip/hip_runtime.h>
#include <hip/hip_bf16.h>
#include <type_traits>

typedef __hip_bfloat16 bf16;
typedef short bf16x8 __attribute__((ext_vector_type(8)));
typedef float f32x4 __attribute__((ext_vector_type(4)));
typedef short short4_ __attribute__((ext_vector_type(4)));

#define NB 8      // batch
#define SM 512    // block size M
#define SL 1024   // attn span L
#define SH 512    // hidden
#define NH 8      // heads
#define HD 64     // head dim
#define SN 1536   // M + L (key length)

static __device__ __forceinline__ short bf_bits(float x) {
  union { bf16 b; short s; } u; u.b = __float2bfloat16(x); return u.s;
}
static __device__ __forceinline__ bf16x8 ld8any(const bf16* p) {
  return *reinterpret_cast<const bf16x8*>(p);
}
static __device__ __forceinline__ bf16x8 ld8any(const float* p) {
  float4 a = *reinterpret_cast<const float4*>(p);
  float4 b = *reinterpret_cast<const float4*>(p + 4);
  bf16x8 r;
  r[0] = bf_bits(a.x); r[1] = bf_bits(a.y); r[2] = bf_bits(a.z); r[3] = bf_bits(a.w);
  r[4] = bf_bits(b.x); r[5] = bf_bits(b.y); r[6] = bf_bits(b.z); r[7] = bf_bits(b.w);
  return r;
}
static __device__ __forceinline__ void st1(bf16* p, float v) { *p = __float2bfloat16(v); }
static __device__ __forceinline__ void st1(float* p, float v) { *p = v; }
static __device__ __forceinline__ f32x4 mfma16(bf16x8 a, bf16x8 b, f32x4 c) {
  return __builtin_amdgcn_mfma_f32_16x16x32_bf16(a, b, c, 0, 0, 0);
}

// ---------------------------------------------------------------------------
// Universal fragment-linear layout for an [R x C] matrix (C = 512):
//   FRAGIDX(row,col) = (row>>4)*8192 + (col>>5)*512
//                    + ((col>>3)&3)*128 + (row&15)*8 + (col&7)
// One wave MFMA fragment (16 rows x 32 cols) = 1KB contiguous, lane*16B.
// ---------------------------------------------------------------------------

// ---------------------------------------------------------------------------
// prep_all: all input conversions, ONE launch, LDS-staged so BOTH the
// f32 row-major reads AND the fragment-linear bf16 writes are coalesced.
//  [0,768)      key   -> kS      [768,1536)  value -> vS
//  [1536,1792)  query -> qS      [1792,1920) W -> Wb
//  [1920,2176)  pe -> peF  (256 blocks = FULL 65536 el)
// ---------------------------------------------------------------------------
__global__ __launch_bounds__(256) void prep_all(
    const float* __restrict__ key, const float* __restrict__ value,
    const float* __restrict__ query,
    const float* __restrict__ Wq, const float* __restrict__ Wk,
    const float* __restrict__ Wv, const float* __restrict__ Wo,
    const float* __restrict__ pe,
    bf16* __restrict__ kS, bf16* __restrict__ vS, bf16* __restrict__ qS,
    bf16* __restrict__ Wb, bf16* __restrict__ peF) {
  __shared__ __align__(16) bf16 t[16 * 520];
  const int id = blockIdx.x, tid = threadIdx.x;
  if (id < 1920) {
    const float* src; bf16* dst;
    if (id < 768)       { src = key   + (size_t)id * 8192;
                          dst = kS    + (size_t)id * 8192; }
    else if (id < 1536) { src = value + (size_t)(id - 768) * 8192;
                          dst = vS    + (size_t)(id - 768) * 8192; }
    else if (id < 1792) { src = query + (size_t)(id - 1536) * 8192;
                          dst = qS    + (size_t)(id - 1536) * 8192; }
    else {
      const int s = id - 1792;
      const float* ws_[4] = {Wq, Wk, Wv, Wo};
      src = ws_[s >> 5] + (size_t)(s & 31) * 8192;
      dst = Wb + (size_t)(s >> 5) * 262144 + (size_t)(s & 31) * 8192;
    }
#pragma unroll
    for (int j = 0; j < 4; ++j) {
      const int i = j * 2048 + tid * 8;
      const bf16x8 v = ld8any(src + i);
      *reinterpret_cast<bf16x8*>(&t[(i >> 9) * 520 + (i & 511)]) = v;
    }
    __syncthreads();
#pragma unroll
    for (int j = 0; j < 4; ++j) {
      const int a = j * 2048 + tid * 8;
      const int kt5 = a >> 9, rest = a & 511;
      const int q = rest >> 7, rowl = (rest >> 3) & 15;
      *reinterpret_cast<bf16x8*>(dst + a) =
          *reinterpret_cast<const bf16x8*>(&t[rowl * 520 + kt5 * 32 + q * 8]);
    }
  } else {
    const int idx = (id - 1920) * 256 + tid;   // 0..65535, full peF
    const int l = idx >> 6, d = idx & 63;
    peF[(size_t)((l >> 4) * 2 + (d >> 5)) * 512
        + (size_t)((((d >> 3) & 3) * 16 + (l & 15)) * 8 + (d & 7))]
      = __float2bfloat16(pe[d * SL + l]);
  }
}

// ---------------------------------------------------------------------------
// gemm_dev2: Y[R x 512] = X @ W^T, X/W fragment-linear, BM=128 x BN=128,
// 4 waves, wave tile 64x64. THREE-deep register pipeline (latency cover ~=
// 2x MFMA per load batch). sched_barrier pins each issue point.
// MODE 0: row-major TY. MODE 1: kF. MODE 2: vF (LDS transpose). MODE 3: qpF.
// ---------------------------------------------------------------------------
#define T2STR 136

#define GL2(AF, BF, KT)                                                      \
  {                                                                          \
    AF[0] = ld8any(xr +         (size_t)(KT) * 512);                         \
    AF[1] = ld8any(xr + 8192  + (size_t)(KT) * 512);                         \
    AF[2] = ld8any(xr + 16384 + (size_t)(KT) * 512);                         \
    AF[3] = ld8any(xr + 24576 + (size_t)(KT) * 512);                         \
    BF[0] = ld8any(wr +         (size_t)(KT) * 512);                         \
    BF[1] = ld8any(wr + 8192  + (size_t)(KT) * 512);                         \
    BF[2] = ld8any(wr + 16384 + (size_t)(KT) * 512);                         \
    BF[3] = ld8any(wr + 24576 + (size_t)(KT) * 512);                         \
  }

#define MF44(AF, BF)                                                         \
  {                                                                          \
    _Pragma("unroll")                                                        \
    for (int mt = 0; mt < 4; ++mt)                                           \
      _Pragma("unroll")                                                      \
      for (int nt = 0; nt < 4; ++nt)                                         \
        acc[mt][nt] = mfma16(AF[mt], BF[nt], acc[mt][nt]);                   \
  }

template <int MODE, typename TY>
static __device__ __forceinline__ void gemm_dev2(const bf16* __restrict__ XF,
                                                 const bf16* __restrict__ WF,
                                                 TY* __restrict__ Y,
                                                 int xblk, int yblk, bf16* tile) {
  const int tid  = threadIdx.x;
  const int lane = tid & 63, w = tid >> 6;
  const int col16 = lane & 15, quad = lane >> 4;
  const int lane8 = lane * 8;
  const int wm = w >> 1, wn = w & 1;
  const int m0 = xblk * 128 + wm * 64;
  const int n0 = yblk * 128 + wn * 64;
  const bf16* xr = XF + (size_t)(m0 >> 4) * 8192 + lane8;
  const bf16* wr = WF + (size_t)(n0 >> 4) * 8192 + lane8;
  f32x4 acc[4][4];
#pragma unroll
  for (int i = 0; i < 4; ++i)
#pragma unroll
    for (int j = 0; j < 4; ++j) acc[i][j] = f32x4{0.f,0.f,0.f,0.f};

  bf16x8 afA[4], bfA[4], afB[4], bfB[4], afC[4], bfC[4];
  GL2(afA, bfA, 0);
  GL2(afB, bfB, 1);
  __builtin_amdgcn_sched_barrier(0);
#pragma unroll
  for (int kt = 0; kt < 16; ++kt) {
    const int nxt = kt + 2;
    if (nxt < 16) {
      if (nxt % 3 == 0)      { GL2(afA, bfA, nxt); }
      else if (nxt % 3 == 1) { GL2(afB, bfB, nxt); }
      else                   { GL2(afC, bfC, nxt); }
      __builtin_amdgcn_sched_barrier(0);
    }
    if (kt % 3 == 0)      MF44(afA, bfA)
    else if (kt % 3 == 1) MF44(afB, bfB)
    else                  MF44(afC, bfC)
  }

  if constexpr (MODE == 0) {
#pragma unroll
    for (int mt = 0; mt < 4; ++mt)
#pragma unroll
      for (int r = 0; r < 4; ++r) {
        const int row = m0 + mt*16 + quad*4 + r;
        TY* yr = Y + (size_t)row * SH + n0 + col16;
#pragma unroll
        for (int nt = 0; nt < 4; ++nt) st1(yr + nt*16, acc[mt][nt][r]);
      }
  } else if constexpr (MODE == 1) {
    // kF: head h = n0>>6; within-half idx = key8 + q*128 + de.
    const int dq = col16 >> 3, de = col16 & 7;
    const int head = n0 >> 6;
#pragma unroll
    for (int mt = 0; mt < 4; ++mt)
#pragma unroll
      for (int r = 0; r < 4; ++r) {
        const int row = m0 + mt*16 + quad*4 + r;
        const int b = row / SN, sr = row - b * SN;
        bf16* yr = (bf16*)Y
            + (((size_t)(b*NH + head)*96 + (sr>>4))*2)*512
            + (size_t)((sr&15)*8 + de);
#pragma unroll
        for (int nt = 0; nt < 4; ++nt)
          yr[(nt>>1)*512 + ((nt&1)*2 + dq)*128] = __float2bfloat16(acc[mt][nt][r]);
      }
  } else if constexpr (MODE == 3) {
    const int dq = col16 >> 3, de = col16 & 7;
    const int c5b = n0 >> 5;
#pragma unroll
    for (int mt = 0; mt < 4; ++mt)
#pragma unroll
      for (int r = 0; r < 4; ++r) {
        bf16* yr = (bf16*)Y + (size_t)((m0>>4) + mt) * 8192
                 + (size_t)((quad*4 + r)*8 + de);
#pragma unroll
        for (int nt = 0; nt < 4; ++nt)
          yr[(c5b + (nt>>1))*512 + ((nt&1)*2 + dq)*128] = __float2bfloat16(acc[mt][nt][r]);
      }
  } else {
    // vF via LDS transpose: tile[d 0..127][row_loc 0..127]
#pragma unroll
    for (int mt = 0; mt < 4; ++mt)
#pragma unroll
      for (int r = 0; r < 4; ++r) {
        const int row_loc = wm*64 + mt*16 + quad*4 + r;
#pragma unroll
        for (int nt = 0; nt < 4; ++nt) {
          const int d = wn*64 + nt*16 + col16;
          tile[d * T2STR + row_loc] = __float2bfloat16(acc[mt][nt][r]);
        }
      }
    __syncthreads();
    const int d  = tid >> 1;      // 0..127
    const int hq = tid & 1;       // 64-row half
    const bf16* src = tile + d * T2STR + hq * 64;
    const int row0 = xblk*128 + hq*64;
    const int b = row0 / SN, sr0 = row0 - b * SN;
    const int head = yblk*2 + (d >> 6);
    const int dd = d & 63;
    bf16* dstF = (bf16*)Y + (((size_t)(b*NH + head)*4 + (dd>>4))*96)*256
               + (size_t)(dd&15)*8;
#pragma unroll
    for (int i = 0; i < 8; ++i) {
      const int key = sr0 + i*8;
      const size_t off = (size_t)(key>>4)*256 + (size_t)((key>>3)&1)*128;
      *reinterpret_cast<uint4*>(dstF + off) = reinterpret_cast<const uint4*>(src)[i];
    }
  }
}

// XCD-aware remap (round-12 proven: FETCH 116->35 MB): within each 32-block
// supergroup, xblk = g*8 + (lid&7), yblk = (lid>>3)&3 -> the 4 blocks
// sharing an X panel are spaced 8 apart in id = same XCD = panel re-reads
// are same-XCD L2 hits.
static __device__ __forceinline__ void xcd_remap(int lid, int& xblk, int& yblk) {
  xblk = (lid >> 5) * 8 + (lid & 7);
  yblk = (lid >> 3) & 3;
}

// Merged K+Q projection: [0,384) K-proj (mode 1), [384,512) Q-proj (mode 3).
__global__ __launch_bounds__(256, 2) void gemmKQ(
    const bf16* __restrict__ XK, const bf16* __restrict__ WK, bf16* __restrict__ YK,
    const bf16* __restrict__ XQ, const bf16* __restrict__ WQ, bf16* __restrict__ YQ) {
  __shared__ bf16 dummy[8];
  const int id = blockIdx.x;
  int xblk, yblk;
  if (id < 384) {
    xcd_remap(id, xblk, yblk);
    gemm_dev2<1, bf16>(XK, WK, YK, xblk, yblk, dummy);
  } else {
    xcd_remap(id - 384, xblk, yblk);   // 384 = 12*32 -> id mod 8 preserved
    gemm_dev2<3, bf16>(XQ, WQ, YQ, xblk, yblk, dummy);
  }
}

__global__ __launch_bounds__(256, 2) void gemmV(
    const bf16* __restrict__ XF, const bf16* __restrict__ WF, bf16* __restrict__ Y) {
  __shared__ __align__(16) bf16 tile[128 * T2STR];
  int xblk, yblk;
  xcd_remap(blockIdx.x, xblk, yblk);
  gemm_dev2<2, bf16>(XF, WF, Y, xblk, yblk, tile);
}

// Fully merged K+Q+V in ONE launch (big-ws tier: vF has its own buffer so
// there is no stgK-reuse ordering hazard). [0,384) K, [384,512) Q, [512,896) V.
__global__ __launch_bounds__(256, 2) void gemmKQV3(
    const bf16* __restrict__ XK, const bf16* __restrict__ WK, bf16* __restrict__ YK,
    const bf16* __restrict__ XQ, const bf16* __restrict__ WQ, bf16* __restrict__ YQ,
    const bf16* __restrict__ XV, const bf16* __restrict__ WV, bf16* __restrict__ YV) {
  __shared__ __align__(16) bf16 tile[128 * T2STR];
  const int id = blockIdx.x;
  int xblk, yblk;
  if (id < 384) {
    xcd_remap(id, xblk, yblk);
    gemm_dev2<1, bf16>(XK, WK, YK, xblk, yblk, tile);
  } else if (id < 512) {
    xcd_remap(id - 384, xblk, yblk);
    gemm_dev2<3, bf16>(XQ, WQ, YQ, xblk, yblk, tile);
  } else {
    xcd_remap(id - 512, xblk, yblk);   // 512 = 16*32 -> id mod 8 preserved
    gemm_dev2<2, bf16>(XV, WV, YV, xblk, yblk, tile);
  }
}

// ---------------------------------------------------------------------------
// gemmO: 64x32 wave tile (BM=128, BN=64), grid 256 -> full-GPU coverage.
// 3-deep register pipeline; id mapping co-locates panel-sharers per XCD.
// ---------------------------------------------------------------------------
#define GLO(AF, BF, KT)                                                      \
  {                                                                          \
    AF[0] = ld8any(xr +         (size_t)(KT) * 512);                         \
    AF[1] = ld8any(xr + 8192  + (size_t)(KT) * 512);                         \
    AF[2] = ld8any(xr + 16384 + (size_t)(KT) * 512);                         \
    AF[3] = ld8any(xr + 24576 + (size_t)(KT) * 512);                         \
    BF[0] = ld8any(wr +         (size_t)(KT) * 512);                         \
    BF[1] = ld8any(wr + 8192  + (size_t)(KT) * 512);                         \
  }

#define MF42(AF, BF)                                                         \
  {                                                                          \
    _Pragma("unroll")                                                        \
    for (int mt = 0; mt < 4; ++mt)                                           \
      _Pragma("unroll")                                                      \
      for (int nt = 0; nt < 2; ++nt)                                         \
        acc[mt][nt] = mfma16(AF[mt], BF[nt], acc[mt][nt]);                   \
  }

__global__ __launch_bounds__(256, 2) void gemmO(
    const bf16* __restrict__ XF, const bf16* __restrict__ WF, float* __restrict__ Y) {
  const int id   = blockIdx.x;
  const int s_   = id >> 3;
  const int xblk = (id & 7) + 8 * (s_ >> 3);
  const int yblk = s_ & 7;
  const int tid  = threadIdx.x;
  const int lane = tid & 63, w = tid >> 6;
  const int col16 = lane & 15, quad = lane >> 4;
  const int lane8 = lane * 8;
  const int wm = w >> 1, wn = w & 1;
  const int m0 = xblk * 128 + wm * 64;
  const int n0 = yblk * 64 + wn * 32;
  const bf16* xr = XF + (size_t)(m0 >> 4) * 8192 + lane8;
  const bf16* wr = WF + (size_t)(n0 >> 4) * 8192 + lane8;
  f32x4 acc[4][2];
#pragma unroll
  for (int i = 0; i < 4; ++i)
#pragma unroll
    for (int j = 0; j < 2; ++j) acc[i][j] = f32x4{0.f,0.f,0.f,0.f};

  bf16x8 afA[4], bfA[2], afB[4], bfB[2], afC[4], bfC[2];
  GLO(afA, bfA, 0);
  GLO(afB, bfB, 1);
  __builtin_amdgcn_sched_barrier(0);
#pragma unroll
  for (int kt = 0; kt < 16; ++kt) {
    const int nxt = kt + 2;
    if (nxt < 16) {
      if (nxt % 3 == 0)      { GLO(afA, bfA, nxt); }
      else if (nxt % 3 == 1) { GLO(afB, bfB, nxt); }
      else                   { GLO(afC, bfC, nxt); }
      __builtin_amdgcn_sched_barrier(0);
    }
    if (kt % 3 == 0)      MF42(afA, bfA)
    else if (kt % 3 == 1) MF42(afB, bfB)
    else                  MF42(afC, bfC)
  }
#pragma unroll
  for (int mt = 0; mt < 4; ++mt)
#pragma unroll
    for (int r = 0; r < 4; ++r) {
      const int row = m0 + mt*16 + quad*4 + r;
      float* yr = Y + (size_t)row * SH + n0 + col16;
      yr[0]  = acc[mt][0][r];
      yr[16] = acc[mt][1][r];
    }
}

// ---------------------------------------------------------------------------
// Barrier-free wave-private fused attention (v14).
// One 64-lane wave owns 16 query rows; grid 2048 x 64 threads.
// v14: BAND-OVERLAP REGISTER ROTATION — chunk ch's kf[4] is chunk ch+1's
// kf[0] (K bands overlap by 16 keys) and vf[dt][2] is the next vf[dt][0]
// (V bands overlap by 32 keys): rotate registers instead of reloading.
// Saves 6 of 30 loads/chunk (20% of vmem slots + L2 requests).
// ---------------------------------------------------------------------------
#define PSTR1 69    // pos stride (f32): scalar writes, b128-aligned reads
#define BSTR1 104   // P stride (bf16): b64 writes, b128 reads aligned

__global__ __launch_bounds__(64, 2) void attn1w(
    const bf16* __restrict__ qp, const bf16* __restrict__ Kh,
    const bf16* __restrict__ VT, const bf16* __restrict__ peT,
    const float* __restrict__ spanv, bf16* __restrict__ ctx) {
  __shared__ __align__(16) float pos_s[16 * PSTR1];
  __shared__ __align__(16) bf16  P_s[16 * BSTR1];

  const int id = blockIdx.x;
  const int h  = id & 7;
  const int s_ = id >> 3;
  const int m0 = (s_ & 31) * 16;
  const int b  = s_ >> 5;
  const int hb = b * 8 + h;
  const int lane  = threadIdx.x;
  const int col16 = lane & 15, quad = lane >> 4, kq = quad << 3;
  const int q4 = quad << 2;
  const int lane8 = lane * 8;

  // zero P band once (cols 80..103 stay zero; read by ks=2 PV fragment)
  for (int i = lane; i < 16 * BSTR1; i += 64)
    P_s[i] = __float2bfloat16(0.0f);

  // q from fragment-linear qp: rt*8192 + h*1024 + lane*8 (and +512)
  const bf16* qb = qp + (size_t)((b*SM + m0) >> 4) * 8192 + h*1024 + lane8;
  const bf16x8 qf0 = ld8any(qb), qf1 = ld8any(qb + 512);

  const bf16* kbF = Kh + (size_t)hb * 98304 + lane8;   // 96 tiles * 1024
  const bf16* vbF = VT + (size_t)hb * 98304 + lane8;   // 4 dt * 96 kt * 256
  const bf16* pbF = peT + lane8;

  float Mrun = -1.0e30f, Srun = 0.0f;
  const float span1024 = spanv[h] * 1024.0f;
  f32x4 o[4];
#pragma unroll
  for (int dt = 0; dt < 4; ++dt) o[dt] = f32x4{0.f,0.f,0.f,0.f};

  // loop-invariant per-lane softmax constants
  float bias_[5][4], mvs_[5][4];
  {
    const float mvb = ((float)(q4 - col16 - 1023) + span1024) * 0.03125f + 1.0f;
#pragma unroll
    for (int t = 0; t < 5; ++t)
#pragma unroll
      for (int r = 0; r < 4; ++r) {
        const int l = 16*t + q4 + r - col16;
        bias_[t][r] = ((unsigned)l < 64u) ? 0.0f : -1.0e30f;
        mvs_[t][r]  = mvb + (float)(16*t + r) * 0.03125f;
      }
  }

  // prefetched operand fragments (single-buffered; WAR ordering via reg deps)
  bf16x8 kf[5][2], pf[4][2], vf[4][3];

  // ---- prologue: chunk-0 operands ----
  {
    const int tk0 = m0 >> 4;
#pragma unroll
    for (int t = 0; t < 5; ++t) {
      const bf16* kr = kbF + (size_t)(tk0 + t) * 1024;
      kf[t][0] = ld8any(kr); kf[t][1] = ld8any(kr + 512);
    }
#pragma unroll
    for (int t = 0; t < 4; ++t) {
      const bf16* pr = pbF + (size_t)t * 1024;
      pf[t][0] = ld8any(pr); pf[t][1] = ld8any(pr + 512);
    }
#pragma unroll
    for (int dt = 0; dt < 4; ++dt) {
      const bf16* v0 = vbF + (size_t)dt * 24576 + (size_t)tk0 * 256;
#pragma unroll
      for (int ks = 0; ks < 3; ++ks) vf[dt][ks] = ld8any(v0 + ks*512);
    }
    __builtin_amdgcn_sched_barrier(0);
  }

  const int posw = col16 * PSTR1 + q4;        // write base (scalar f32)
  const int posr = col16 * (PSTR1 - 1) + q4;  // read base (b128-aligned)
  const int pww  = col16 * BSTR1 + q4;        // P write base (b64-aligned)
  const int pwr  = col16 * BSTR1 + kq;        // P read base (b128-aligned)

  for (int ch = 0; ch < 16; ++ch) {
    const int l0 = ch << 6;

    // ---- pos MFMAs (swapped: A=pe rows, D rows = l, cols = q-row) ----
    f32x4 pacc[4];
#pragma unroll
    for (int t = 0; t < 4; ++t) {
      f32x4 a = {0.f,0.f,0.f,0.f};
      a = mfma16(pf[t][0], qf0, a);
      a = mfma16(pf[t][1], qf1, a);
      pacc[t] = a;
    }
#pragma unroll
    for (int t = 0; t < 4; ++t)
#pragma unroll
      for (int r = 0; r < 4; ++r)
        pos_s[posw + 16*t + r] = pacc[t][r];

    // ---- cont MFMAs (swapped: A=K rows, D rows = band pos, cols = q-row) ----
    f32x4 cacc[5];
#pragma unroll
    for (int t = 0; t < 5; ++t) {
      f32x4 a = {0.f,0.f,0.f,0.f};
      a = mfma16(kf[t][0], qf0, a);
      a = mfma16(kf[t][1], qf1, a);
      cacc[t] = a;
    }

    // ---- issue next chunk's K/pe (kf/pf regs now dead); pinned.
    //      v14: kf[0]' == kf[4] (band overlap) -> rotate, load only t=1..4.
    {
      const int l0n = (ch < 15) ? l0 + 64 : l0;  // ch==15: dead reload
      const int tkn = (m0 + l0n) >> 4;
      const int tpn = l0n >> 4;
      const bf16x8 kc0 = kf[4][0], kc1 = kf[4][1];
#pragma unroll
      for (int t = 1; t < 5; ++t) {
        const bf16* kr = kbF + (size_t)(tkn + t) * 1024;
        kf[t][0] = ld8any(kr); kf[t][1] = ld8any(kr + 512);
      }
      kf[0][0] = kc0; kf[0][1] = kc1;
#pragma unroll
      for (int t = 0; t < 4; ++t) {
        const bf16* pr = pbF + (size_t)(tpn + t) * 1024;
        pf[t][0] = ld8any(pr); pf[t][1] = ld8any(pr + 512);
      }
      __builtin_amdgcn_sched_barrier(0);
    }

    // ---- per-lane softmax over this row's 64-key window ----
    float sc[5][4];
    float mc = -1.0e30f;
#pragma unroll
    for (int t = 0; t < 5; ++t) {
      const f32x4 pv4 = *reinterpret_cast<const f32x4*>(&pos_s[posr + 16*t]);
#pragma unroll
      for (int r = 0; r < 4; ++r) {
        const float v = fmaf(cacc[t][r] + pv4[r], 0.125f, bias_[t][r]);
        sc[t][r] = v;
        mc = fmaxf(mc, v);
      }
    }
    mc = fmaxf(mc, __shfl_xor(mc, 16));
    mc = fmaxf(mc, __shfl_xor(mc, 32));
    const float Mnew = fmaxf(Mrun, mc);
    const bool defer = __all(Mnew - Mrun <= 8.0f);
    const float Mb = defer ? Mrun : Mnew;      // wave-uniform select
    const float chf = (float)ch * 2.0f;        // l0 * 0.03125
    float ls = 0.0f;
#pragma unroll
    for (int t = 0; t < 5; ++t) {
      short4_ pk;
#pragma unroll
      for (int r = 0; r < 4; ++r) {
        const float p = __expf(sc[t][r] - Mb);  // 0 for masked slots
        ls += p;
        float mv = mvs_[t][r] + chf;
        mv = fminf(fmaxf(mv, 0.0f), 1.0f);
        pk[r] = bf_bits(p * mv);
      }
      *reinterpret_cast<short4_*>(&P_s[pww + 16*t]) = pk;
    }
    ls += __shfl_xor(ls, 16);
    ls += __shfl_xor(ls, 32);

    if (defer) {
      Srun += ls;                 // no rescale, Mrun unchanged
    } else {
      const float alpha = __expf(Mrun - Mnew);
      Srun = Srun * alpha + ls;
      Mrun = Mnew;
#pragma unroll
      for (int dt = 0; dt < 4; ++dt)
#pragma unroll
        for (int r = 0; r < 4; ++r) o[dt][r] *= alpha;
    }

    // ---- PV (swapped: A=V^T rows=d, B=P cols=q-row) ----
#pragma unroll
    for (int ks = 0; ks < 3; ++ks) {
      const bf16x8 ap = ld8any(&P_s[pwr + ks*32]);
#pragma unroll
      for (int dt = 0; dt < 4; ++dt)
        o[dt] = mfma16(vf[dt][ks], ap, o[dt]);
    }

    // ---- issue next chunk's V (vf regs now dead); pinned.
    //      v14: vf[dt][0]' == vf[dt][2] (32-key overlap) -> rotate,
    //      load only ks=1..2.
    {
      const int tkn = (m0 + ((ch < 15) ? l0 + 64 : l0)) >> 4;
#pragma unroll
      for (int dt = 0; dt < 4; ++dt) {
        const bf16x8 vc = vf[dt][2];
        const bf16* v0 = vbF + (size_t)dt * 24576 + (size_t)tkn * 256;
        vf[dt][1] = ld8any(v0 + 512);
        vf[dt][2] = ld8any(v0 + 1024);
        vf[dt][0] = vc;
      }
      __builtin_amdgcn_sched_barrier(0);
    }
  }

  // ---- epilogue: lane-local normalize, fragment-linear ctx stores ----
  const float inv = 1.0f / Srun;
  bf16* crb = ctx + (size_t)((b*SM + m0) >> 4) * 8192
            + (size_t)(h*1024 + (quad>>1)*128 + col16*8 + (quad&1)*4);
#pragma unroll
  for (int dt = 0; dt < 4; ++dt) {
    short4_ pk;
#pragma unroll
    for (int r = 0; r < 4; ++r) pk[r] = bf_bits(o[dt][r] * inv);
    *reinterpret_cast<short4_*>(crb + (size_t)(dt>>1)*512 + (dt&1)*256) = pk;
  }
}

// ---------------------------------------------------------------------------
// Fallback path kernels (round-6 proven, old row-major layouts).
// ---------------------------------------------------------------------------
template <int MODE, typename TX, typename TW, typename TY>
__global__ __launch_bounds__(256) void gemmbn64(const TX* __restrict__ X,
                                                const TW* __restrict__ W,
                                                TY* __restrict__ Y) {
  __shared__ __align__(16) bf16 tile[(MODE == 2) ? 64 * T2STR : 8];
  const int id   = blockIdx.x;
  const int s_   = id >> 3;
  const int xblk = (id & 7) + 8 * (s_ >> 3);
  const int yblk = s_ & 7;
  const int tid  = threadIdx.x;
  const int lane = tid & 63, w = tid >> 6;
  const int col16 = lane & 15, quad = lane >> 4, kq = quad << 3;
  const int wm = w >> 1, wn = w & 1;
  const int m0 = xblk * 128 + wm * 64;
  const int n0 = yblk * 64 + wn * 32;
  const TX* xr = X + (size_t)(m0 + col16) * SH + kq;
  const TW* wr = W + (size_t)(n0 + col16) * SH + kq;
  f32x4 acc[4][2];
#pragma unroll
  for (int i = 0; i < 4; ++i)
#pragma unroll
    for (int j = 0; j < 2; ++j) acc[i][j] = f32x4{0.f,0.f,0.f,0.f};
#pragma unroll
  for (int k0 = 0; k0 < SH; k0 += 32) {
    bf16x8 af[4], bfr[2];
#pragma unroll
    for (int t = 0; t < 4; ++t) af[t]  = ld8any(xr + (size_t)(t*16) * SH + k0);
#pragma unroll
    for (int t = 0; t < 2; ++t) bfr[t] = ld8any(wr + (size_t)(t*16) * SH + k0);
#pragma unroll
    for (int mt = 0; mt < 4; ++mt)
#pragma unroll
      for (int nt = 0; nt < 2; ++nt)
        acc[mt][nt] = mfma16(af[mt], bfr[nt], acc[mt][nt]);
  }

  if constexpr (MODE == 0) {
#pragma unroll
    for (int mt = 0; mt < 4; ++mt)
#pragma unroll
      for (int r = 0; r < 4; ++r) {
        const int row = m0 + mt*16 + quad*4 + r;
        TY* yr = Y + (size_t)row * SH + n0 + col16;
        st1(yr,      acc[mt][0][r]);
        st1(yr + 16, acc[mt][1][r]);
      }
  } else if constexpr (MODE == 1) {
#pragma unroll
    for (int mt = 0; mt < 4; ++mt)
#pragma unroll
      for (int r = 0; r < 4; ++r) {
        const int row = m0 + mt*16 + quad*4 + r;
        const int b = row / SN, sr = row - b * SN;
        bf16* yr = (bf16*)Y + (size_t)((b*NH + yblk)*SN + sr) * HD
                 + wn*32 + col16;
        yr[0]  = __float2bfloat16(acc[mt][0][r]);
        yr[16] = __float2bfloat16(acc[mt][1][r]);
      }
  } else {
#pragma unroll
    for (int mt = 0; mt < 4; ++mt)
#pragma unroll
      for (int r = 0; r < 4; ++r) {
        const int row_loc = wm*64 + mt*16 + quad*4 + r;
#pragma unroll
        for (int nt = 0; nt < 2; ++nt) {
          const int d = wn*32 + nt*16 + col16;
          tile[d * T2STR + row_loc] = __float2bfloat16(acc[mt][nt][r]);
        }
      }
    __syncthreads();
    const int d  = tid >> 2;
    const int hq = tid & 3;
    const bf16* src = tile + d * T2STR + hq * 32;
    const int row0 = xblk*128 + hq*32;
    const int b = row0 / SN, sr0 = row0 - b * SN;
    bf16* dst = (bf16*)Y + (size_t)((b*NH + yblk)*HD + d) * SN + sr0;
#pragma unroll
    for (int i = 0; i < 4; ++i)
      reinterpret_cast<uint4*>(dst)[i] = reinterpret_cast<const uint4*>(src)[i];
  }
}

__global__ void transpose_pe_fb(const float* __restrict__ pe, bf16* __restrict__ peT) {
  int idx = blockIdx.x * 256 + threadIdx.x;
  int l = idx >> 6, d = idx & 63;
  peT[idx] = __float2bfloat16(pe[d * SL + l]);
}

#define MT 16
#define CSTR 84
#define PSTR 65
#define BSTR 104
#define QSTR 72

__global__ __launch_bounds__(128) void attn_kernel_fb(
    const float* __restrict__ query, const float* __restrict__ Wq,
    const bf16* __restrict__ Kh, const bf16* __restrict__ VT,
    const bf16* __restrict__ peT, const float* __restrict__ spanv,
    bf16* __restrict__ ctx) {
  __shared__ __align__(16) float cont_lds[MT][CSTR];
  __shared__ __align__(16) float pos_lds[MT][PSTR];
  __shared__ __align__(16) bf16  P_lds[MT][BSTR];
  __shared__ __align__(16) bf16  q_lds[MT*QSTR];
  __shared__ float alpha_lds[MT];
  __shared__ float S_lds[MT];

  const int id = blockIdx.x;
  const int h  = id & 7;
  const int s_ = id >> 3;
  const int m0 = (s_ & 31) * MT;
  const int b  = s_ >> 5;
  const int hb = b * 8 + h;
  const int tid  = threadIdx.x;
  const int lane = tid & 63;
  const int w    = tid >> 6;
  const int col16 = lane & 15, quad = lane >> 4, kq = quad << 3;
  const int wr = quad << 2;

  for (int i = tid; i < MT * BSTR; i += 128)
    (&P_lds[0][0])[i] = __float2bfloat16(0.0f);

  bf16x8 qf0, qf1;
  {
    f32x4 qa0 = {0.f,0.f,0.f,0.f}, qa1 = qa0;
    const float* xq = query + (size_t)(b*SM + m0 + col16) * SH + kq;
    const float* w0 = Wq + (size_t)(h*HD + w*32 + col16) * SH + kq;
    const float* w1 = w0 + (size_t)16 * SH;
#pragma unroll
    for (int k0 = 0; k0 < SH; k0 += 32) {
      bf16x8 xa = ld8any(xq + k0);
      qa0 = mfma16(xa, ld8any(w0 + k0), qa0);
      qa1 = mfma16(xa, ld8any(w1 + k0), qa1);
    }
#pragma unroll
    for (int r = 0; r < 4; ++r) {
      q_lds[(wr + r)*QSTR + w*32 + col16]      = __float2bfloat16(qa0[r]);
      q_lds[(wr + r)*QSTR + w*32 + 16 + col16] = __float2bfloat16(qa1[r]);
    }
    __syncthreads();
    qf0 = ld8any(&q_lds[col16*QSTR + kq]);
    qf1 = ld8any(&q_lds[col16*QSTR + kq + 32]);
  }

  const bf16* kb = Kh + (size_t)(hb * SN) * HD + kq;
  const bf16* vb = VT + (size_t)(hb * HD) * SN;

  const int srow = tid >> 3, sj = tid & 7;
  float Mrun = -1.0e30f, Srun = 0.0f;
  const float span = spanv[h];
  const int dt0 = w * 16, dt1 = (w + 2) * 16;
  f32x4 o0 = {0.f,0.f,0.f,0.f}, o1 = o0;

  for (int ch = 0; ch < 16; ++ch) {
    const int l0 = ch << 6;
    const int nb_ = m0 + l0;

    f32x4 ca0 = {0.f,0.f,0.f,0.f}, ca1 = ca0, ca2 = ca0, pa0 = ca0, pa1 = ca0;
    {
      const bf16* kr0 = kb + (size_t)(nb_ + w*16 + col16) * HD;
      ca0 = mfma16(qf0, ld8any(kr0),           ca0);
      ca0 = mfma16(qf1, ld8any(kr0 + 32),      ca0);
      const bf16* kr1 = kr0 + 32 * HD;
      ca1 = mfma16(qf0, ld8any(kr1),           ca1);
      ca1 = mfma16(qf1, ld8any(kr1 + 32),      ca1);
      if (w == 0) {
        const bf16* kr2 = kr0 + 64 * HD;
        ca2 = mfma16(qf0, ld8any(kr2),         ca2);
        ca2 = mfma16(qf1, ld8any(kr2 + 32),    ca2);
      }
      const bf16* pr0 = peT + (size_t)(l0 + w*16 + col16) * HD + kq;
      pa0 = mfma16(qf0, ld8any(pr0),           pa0);
      pa0 = mfma16(qf1, ld8any(pr0 + 32),      pa0);
      const bf16* pr1 = pr0 + 32 * HD;
      pa1 = mfma16(qf0, ld8any(pr1),           pa1);
      pa1 = mfma16(qf1, ld8any(pr1 + 32),      pa1);
    }
#pragma unroll
    for (int r = 0; r < 4; ++r) {
      cont_lds[wr + r][w*16 + col16]      = ca0[r];
      cont_lds[wr + r][w*16 + 32 + col16] = ca1[r];
      if (w == 0) cont_lds[wr + r][64 + col16] = ca2[r];
      pos_lds[wr + r][w*16 + col16]       = pa0[r];
      pos_lds[wr + r][w*16 + 32 + col16]  = pa1[r];
    }
    __syncthreads();

    float sc[8];
    float mc = -1.0e30f;
    const float* crow = &cont_lds[srow][srow + sj*8];
    const float* prow = &pos_lds[srow][sj*8];
#pragma unroll
    for (int i = 0; i < 8; ++i) {
      float v = (crow[i] + prow[i]) * 0.125f;
      sc[i] = v;
      mc = fmaxf(mc, v);
    }
    mc = fmaxf(mc, __shfl_xor(mc, 1));
    mc = fmaxf(mc, __shfl_xor(mc, 2));
    mc = fmaxf(mc, __shfl_xor(mc, 4));
    const float Mnew = fmaxf(Mrun, mc);
    const float alpha = __expf(Mrun - Mnew);
    float ls = 0.0f;
    bf16* pwrow = &P_lds[srow][srow + sj*8];
#pragma unroll
    for (int i = 0; i < 8; ++i) {
      float p = __expf(sc[i] - Mnew);
      ls += p;
      const float tpl = (float)(l0 + sj*8 + i) - 1023.0f;
      float mv = (tpl + span * 1024.0f) * 0.03125f + 1.0f;
      mv = fminf(fmaxf(mv, 0.0f), 1.0f);
      pwrow[i] = __float2bfloat16(p * mv);
    }
    ls += __shfl_xor(ls, 1);
    ls += __shfl_xor(ls, 2);
    ls += __shfl_xor(ls, 4);
    Srun = Srun * alpha + ls;
    Mrun = Mnew;
    if (sj == 0) { alpha_lds[srow] = alpha; S_lds[srow] = Srun; }
    __syncthreads();

    float al[4];
#pragma unroll
    for (int r = 0; r < 4; ++r) al[r] = alpha_lds[wr + r];
#pragma unroll
    for (int r = 0; r < 4; ++r) { o0[r] *= al[r]; o1[r] *= al[r]; }
#pragma unroll
    for (int ks = 0; ks < 3; ++ks) {
      const bf16x8 ap = ld8any(&P_lds[col16][ks*32 + kq]);
      const bf16* v0 = vb + (size_t)(dt0 + col16) * SN + nb_ + ks*32 + kq;
      const bf16* v1 = vb + (size_t)(dt1 + col16) * SN + nb_ + ks*32 + kq;
      o0 = mfma16(ap, ld8any(v0), o0);
      o1 = mfma16(ap, ld8any(v1), o1);
    }
  }

  bf16* cr = ctx + (size_t)(b*SM + m0 + wr) * SH + h*HD + col16;
#pragma unroll
  for (int r = 0; r < 4; ++r) {
    const float inv = 1.0f / S_lds[wr + r];
    cr[(size_t)r * SH + dt0] = __float2bfloat16(o0[r] * inv);
    cr[(size_t)r * SH + dt1] = __float2bfloat16(o1[r] * inv);
  }
}

// ---------------------------------------------------------------------------
extern "C" void kernel_launch(void* const* d_in, const int* in_sizes, int n_in,
                              void* d_out, int out_size, void* d_ws, size_t ws_size,
                              hipStream_t stream) {
  const float* query  = (const float*)d_in[0];
  const float* key    = (const float*)d_in[1];
  const float* value  = (const float*)d_in[2];
  const float* key_pe = (const float*)d_in[3];
  const float* Wq     = (const float*)d_in[4];
  const float* Wk     = (const float*)d_in[5];
  const float* Wv     = (const float*)d_in[6];
  const float* Wo     = (const float*)d_in[7];
  const float* spanv  = (const float*)d_in[8];
  float* out = (float*)d_out;

  bf16* ws = (bf16*)d_ws;
  if (ws_size >= (size_t)60948480) {
    // Path D: big workspace — vF gets its own buffer, so K/Q/V projections
    // are fully independent and merge into ONE launch (4 launches total).
    bf16* B0   = ws;                      // stgK
    bf16* B1   = B0  + 6291456;           // stgV
    bf16* B2   = B1  + 6291456;           // kF
    bf16* B3   = B2  + 6291456;           // vF
    bf16* qp   = B3  + 6291456;           // qpF
    bf16* ctxC = qp  + 2097152;           // qS staging, then attn ctx
    bf16* peF  = ctxC + 2097152;
    bf16* Wb   = peF + 65536;
    bf16* Wq_b = Wb, *Wk_b = Wb + 262144, *Wv_b = Wb + 524288, *Wo_b = Wb + 786432;

    prep_all<<<2176, 256, 0, stream>>>(key, value, query, Wq, Wk, Wv, Wo,
                                       key_pe, B0, B1, ctxC, Wb, peF);
    gemmKQV3<<<896, 256, 0, stream>>>(B0, Wk_b, B2, ctxC, Wq_b, qp,
                                      B1, Wv_b, B3);
    attn1w<<<2048, 64, 0, stream>>>(qp, B2, B3, peF, spanv, ctxC);
    gemmO<<<256, 256, 0, stream>>>(ctxC, Wo_b, out);
  } else if (ws_size >= (size_t)48365568) {
    // Path C: round-13 proven pipeline (vF reuses stgK -> serialized GEMMs).
    bf16* B0   = ws;                      // stgK -> vF
    bf16* B1   = B0  + 6291456;           // stgV
    bf16* B2   = B1  + 6291456;           // kF
    bf16* qp   = B2  + 6291456;           // qpF
    bf16* ctxC = qp  + 2097152;           // qS staging, then attn ctx
    bf16* peF  = ctxC + 2097152;
    bf16* Wb   = peF + 65536;
    bf16* Wq_b = Wb, *Wk_b = Wb + 262144, *Wv_b = Wb + 524288, *Wo_b = Wb + 786432;

    prep_all<<<2176, 256, 0, stream>>>(key, value, query, Wq, Wk, Wv, Wo,
                                       key_pe, B0, B1, ctxC, Wb, peF);
    gemmKQ<<<512, 256, 0, stream>>>(B0, Wk_b, B2, ctxC, Wq_b, qp);
    gemmV<<<384, 256, 0, stream>>>(B1, Wv_b, B0);
    attn1w<<<2048, 64, 0, stream>>>(qp, B2, B0, peF, spanv, ctxC);
    gemmO<<<256, 256, 0, stream>>>(ctxC, Wo_b, out);
  } else {
    // Path B (fallback): fused-q attention, f32 GEMM reads, 29.5 MB ws.
    bf16* k_head = ws;
    bf16* vT     = k_head + 6291456;
    bf16* ctx    = vT     + 6291456;
    bf16* peT    = ctx    + 2097152;
    gemmbn64<1, float, float, bf16><<<768, 256, 0, stream>>>(key,   Wk, k_head);
    gemmbn64<2, float, float, bf16><<<768, 256, 0, stream>>>(value, Wv, vT);
    transpose_pe_fb<<<256, 256, 0, stream>>>(key_pe, peT);
    attn_kernel_fb<<<2048, 128, 0, stream>>>(query, Wq, k_head, vT,
                                             peT, spanv, ctx);
    gemmbn64<0, bf16, float, float><<<256, 256, 0, stream>>>(ctx, Wo, out);
  }
}